// Round 6
// baseline (219.829 us; speedup 1.0000x reference)
//
#include <hip/hip_runtime.h>
#include <math.h>

// ---------------- problem constants ----------------
#define TTD 1024
#define DDM 1024
#define HDIM 64
#define PSCALE 0.125f
// PSCALE * log2(e): flash softmax runs in exp2 domain
#define PSC2 0.18033688011112042f
#define LS 72   // padded LDS stride (wraw_solveA)

typedef __attribute__((ext_vector_type(8))) __bf16 bf16x8;
typedef __attribute__((ext_vector_type(4))) float f32x4;
#define MFMA16(a,b,c) __builtin_amdgcn_mfma_f32_16x16x32_bf16(a,b,c,0,0,0)

// counted vmcnt wait + raw barriers
#define STR_(x) #x
#define WAITVM(N) asm volatile("s_waitcnt vmcnt(" STR_(N) ")" ::: "memory")
#define BAR() do { __builtin_amdgcn_s_barrier(); asm volatile("" ::: "memory"); } while (0)
#define LGKBAR() do { asm volatile("s_waitcnt lgkmcnt(0)" ::: "memory"); \
                      __builtin_amdgcn_s_barrier(); asm volatile("" ::: "memory"); } while (0)
#define FULLBAR() do { asm volatile("s_waitcnt vmcnt(0) lgkmcnt(0)" ::: "memory"); \
                       __builtin_amdgcn_s_barrier(); asm volatile("" ::: "memory"); } while (0)

__device__ __forceinline__ ushort f2b(float f) {
  unsigned u = __builtin_bit_cast(unsigned, f);
  return (ushort)((u + 0x7fffu + ((u >> 16) & 1u)) >> 16);
}
__device__ __forceinline__ float b2f(ushort u) {
  unsigned v = (unsigned)u << 16;
  return __builtin_bit_cast(float, v);
}

__device__ __forceinline__ void gload_lds16(const ushort* g, ushort* l) {
  __builtin_amdgcn_global_load_lds(
      (const __attribute__((address_space(1))) unsigned*)g,
      (__attribute__((address_space(3))) unsigned*)l, 16, 0, 0);
}

// XOR-swizzled 64x64 bf16 tile: 16B slot index for (row, chunk)
#define SWZ(row, cc) (((row) * 8 + ((cc) ^ ((row) & 7))) * 8)
#define SWZE(row, col) (SWZ(row, (col) >> 3) + ((col) & 7))
// transpose-write-friendly swizzle (solveB WT only): key = (row&7)^(row>>3).
#define SWZ2(row, cc) (((row) * 8 + ((cc) ^ (((row) & 7) ^ ((row) >> 3)))) * 8)
#define SWZ2E(row, col) (SWZ2(row, (col) >> 3) + ((col) & 7))

// async-stage one 64x64 tile (rows at gs-elem stride) into swizzled LDS tile
// issues exactly 2 global_load_lds instructions per thread
__device__ __forceinline__ void stage_tile(const ushort* gb, long gs, ushort* tile,
                                           int w, int l) {
  int sub = l >> 3, cc = (l & 7) ^ sub;
  #pragma unroll
  for (int it = 0; it < 2; ++it) {
    int q = w * 2 + it;
    gload_lds16(gb + (long)(q * 8 + sub) * gs + cc * 8, &tile[(q * 64 + l) * 8]);
  }
}

__device__ __forceinline__ bf16x8 frag(const ushort* tile, int row, int cc) {
  return *(const bf16x8*)&tile[SWZ(row, cc)];
}
__device__ __forceinline__ bf16x8 frag2(const ushort* tile, int row, int cc) {
  return *(const bf16x8*)&tile[SWZ2(row, cc)];
}

// ---------------- workspace layout (bytes); total used = 121,896,960 ----------
#define XT_PERH   557056L       // packed-UT X elems per head (136*4096)
#define OFF_X     0L            // 35,651,584 B
#define OFF_PZ    35651584L     // KZ bf16 [32][15][1024 j][64 d] : 60 MiB
// aliases inside KZ region (all dead before solveB writes KZ):
#define OFF_HSB   35651584L
#define OFF_QWW   37748736L
#define OFF_KWW   39845888L
#define OFF_VWW   41943040L
#define OFF_W2B   44040192L
#define OFF_WLOWB 44302336L
#define OFF_TB    98566144L     // Tbeta bf16 (wraw_solveA->solveB); dead after solveB
#define OFF_OALL  98566144L     // o_all overlays TB (flash writes after solveB)
#define OFF_YB    102760448L    // Yb bf16 (wraw_solveA->solveB)
#define OFF_OWB   106954752L    // ow_b own region: converted at t=0 by cvt_all
#define OFF_WHB   111149056L    // wh bf16 (live through flash)
#define OFF_QB    115343360L
#define OFF_KB    117440512L
#define OFF_VTB   119537664L
#define OFF_BETA  121634816L
#define OFF_BW64  121765888L    // 64x1024 bf16 [bt_w ; w1]

// ---------------- merged fp32 -> bf16 convert (8 segments, one launch) ----------------
#define CVT_TOTAL 6488064L
struct CvtSegs {
  const float* src[8];
  ushort* dst[8];
  long cnt[8];
};
__global__ __launch_bounds__(256) void cvt_all_kernel(CvtSegs sg) {
  long e = ((long)blockIdx.x * 256 + threadIdx.x) * 4;
  #pragma unroll
  for (int s = 0; s < 8; ++s) {
    if (e < sg.cnt[s]) {
      float4 f = *(const float4*)(sg.src[s] + e);
      ushort4 o;
      o.x = f2b(f.x); o.y = f2b(f.y); o.z = f2b(f.z); o.w = f2b(f.w);
      *(ushort4*)(sg.dst[s] + e) = o;
      return;
    }
    e -= sg.cnt[s];
  }
}

// ---------------- fused QKV + small projections: z in {Q,K,V, small} ----------------
// BM=128 x BN=64; SINGLE-barrier pipeline: {WAITVM(0); BAR; stage next->freed buf; MFMA}
// (the loads waited on were issued a full compute-phase ago -> drain is free)
__global__ __launch_bounds__(256) void qkv_sp_kernel(
    const ushort* __restrict__ hsb,
    const ushort* __restrict__ wq, const ushort* __restrict__ wk, const ushort* __restrict__ wv,
    const ushort* __restrict__ bw, const float* __restrict__ bt_b,
    ushort* __restrict__ cq, ushort* __restrict__ ck, ushort* __restrict__ cv,
    float* __restrict__ beta, ushort* __restrict__ wlowb)
{
  int z = blockIdx.z;
  if (z == 3 && blockIdx.x != 0) return;
  const ushort* B = (z == 0) ? wq : (z == 1) ? wk : (z == 2) ? wv : bw;

  __shared__ ushort Ab[2][8192];   // two stacked swizzled 64x64 tiles (128 rows)
  __shared__ ushort Bb[2][4096];

  int tid = threadIdx.x, w = tid >> 6, l = tid & 63;
  int quad = l >> 4, lane15 = l & 15;
  int rm = blockIdx.y * 128, cn = (z == 3) ? 0 : blockIdx.x * 64;
  const ushort* Ag = hsb + (long)rm * DDM;
  const ushort* Bg = B + (long)cn * DDM;

  // prologue: stage tile 0 (6 vm insts)
  stage_tile(Ag, DDM, &Ab[0][0], w, l);
  stage_tile(Ag + 64 * DDM, DDM, &Ab[0][4096], w, l);
  stage_tile(Bg, DDM, &Bb[0][0], w, l);

  f32x4 acc[2][4] = {};
  int arow0 = (w & 1) * 32 + lane15;
  int asel = (w >> 1) * 4096;
  for (int kt = 0; kt < 16; ++kt) {
    int cur = kt & 1;
    WAITVM(0);         // own prev-tile loads landed (issued one full phase ago)
    BAR();             // joins all waves; frees buffer [cur^1] (read last iter)
    if (kt < 15) {
      int nxt = cur ^ 1;
      stage_tile(Ag + (kt + 1) * 64, DDM, &Ab[nxt][0], w, l);
      stage_tile(Ag + 64 * DDM + (kt + 1) * 64, DDM, &Ab[nxt][4096], w, l);
      stage_tile(Bg + (kt + 1) * 64, DDM, &Bb[nxt][0], w, l);
    }
    const ushort* Atile = &Ab[cur][asel];
    #pragma unroll
    for (int s = 0; s < 2; ++s) {
      bf16x8 a0 = frag(Atile, arow0, s * 4 + quad);
      bf16x8 a1 = frag(Atile, arow0 + 16, s * 4 + quad);
      #pragma unroll
      for (int f = 0; f < 4; ++f) {
        bf16x8 bf = frag(&Bb[cur][0], f * 16 + lane15, s * 4 + quad);
        acc[0][f] = MFMA16(a0, bf, acc[0][f]);
        acc[1][f] = MFMA16(a1, bf, acc[1][f]);
      }
    }
  }

  if (z < 2) {
    ushort* Cb = (z == 0) ? cq : ck;
    #pragma unroll
    for (int rr = 0; rr < 2; ++rr) {
      int orow = rm + w * 32 + rr * 16 + quad * 4;
      #pragma unroll
      for (int f = 0; f < 4; ++f)
        #pragma unroll
        for (int r = 0; r < 4; ++r)
          Cb[(long)(orow + r) * DDM + cn + f * 16 + lane15] = f2b(acc[rr][f][r]);
    }
  } else if (z == 2) {
    #pragma unroll
    for (int rr = 0; rr < 2; ++rr) {
      int orow = rm + w * 32 + rr * 16 + quad * 4;
      #pragma unroll
      for (int f = 0; f < 4; ++f) {
        ushort4 o;
        o.x = f2b(acc[rr][f][0]); o.y = f2b(acc[rr][f][1]);
        o.z = f2b(acc[rr][f][2]); o.w = f2b(acc[rr][f][3]);
        *(ushort4*)&cv[(long)(cn + f * 16 + lane15) * TTD + orow] = o;
      }
    }
  } else {
    #pragma unroll
    for (int rr = 0; rr < 2; ++rr) {
      int orow = rm + w * 32 + rr * 16 + quad * 4;
      #pragma unroll
      for (int f = 0; f < 2; ++f) {
        int hr = f * 16 + lane15;
        float bb = bt_b[hr];
        #pragma unroll
        for (int r = 0; r < 4; ++r)
          beta[(long)hr * TTD + orow + r] = 2.f / (1.f + __expf(-(acc[rr][f][r] + bb)));
      }
      #pragma unroll
      for (int f = 2; f < 4; ++f)
        #pragma unroll
        for (int r = 0; r < 4; ++r)
          wlowb[(long)(orow + r) * 32 + (f - 2) * 16 + lane15] = f2b(acc[rr][f][r]);
    }
  }
}

// ---------------- FUSED: w_raw GEMM + conv + SiLU + rotate + normalize + solveA -------------
__global__ __launch_bounds__(256) void wraw_solveA_kernel(
    const ushort* __restrict__ wlowb, const ushort* __restrict__ w2b,
    const float* __restrict__ conv_w, const float* __restrict__ omega,
    const float* __restrict__ phi, const float* __restrict__ beta,
    ushort* __restrict__ whb, ushort* __restrict__ TB, ushort* __restrict__ YB)
{
  int c = blockIdx.x;
  int rm = c * 64;
  int p = blockIdx.y;             // head hr
  int hkv = p >> 1, r = p & 1;
  int c0 = hkv * 256 + r * 128;

  __shared__ char pool_[65568];
  ushort* As = (ushort*)pool_;
  ushort* Bs = (ushort*)(pool_ + 4096);
  float (*WR)[132] = (float(*)[132])(pool_ + 12288);
  ushort* Wrow = (ushort*)(pool_ + 47136);   // wh row-major [t][d], stride LS
  ushort* WT   = (ushort*)(pool_ + 56352);   // wh transposed [d][t], stride LS
  float (*Lm)[65] = (float(*)[65])pool_;
  float (*Vf)[65] = (float(*)[65])(pool_ + 16640);
  ushort* Tb = (ushort*)(pool_ + 33280);

  int tid = threadIdx.x, w = tid >> 6, l = tid & 63;
  int quad = l >> 4, lane15 = l & 15;

  // ---- phase 1: async-stage A (w_low rows) + B (w2 rows, 128) ----
  {
    int row = tid >> 2, ch = (tid & 3) * 8;
    gload_lds16(wlowb + (long)(rm + row) * 32 + ch, &As[row * 32 + ch]);
    gload_lds16(w2b + (long)(c0 + row) * 32 + ch, &Bs[row * 32 + ch]);
    gload_lds16(w2b + (long)(c0 + 64 + row) * 32 + ch, &Bs[(64 + row) * 32 + ch]);
  }
  // halo rows rm-2, rm-1 (VALU dot; zero when rm==0 -> causal pad)
  {
    int hr2 = tid >> 7, col = tid & 127;
    float acc = 0.f;
    if (rm > 0) {
      long t = rm - 2 + hr2;
      for (int k = 0; k < 32; ++k)
        acc += b2f(wlowb[t * 32 + k]) * b2f(w2b[(long)(c0 + col) * 32 + k]);
    }
    WR[hr2][col] = acc;
  }
  FULLBAR();   // async stage consumed next

  // ---- phase 2: main 64x128 GEMM via MFMA (two 64-col halves) ----
  #pragma unroll
  for (int g = 0; g < 2; ++g) {
    f32x4 acc[4] = {};
    bf16x8 af = *(const bf16x8*)&As[(w * 16 + lane15) * 32 + quad * 8];
    #pragma unroll
    for (int f = 0; f < 4; ++f) {
      bf16x8 bf = *(const bf16x8*)&Bs[(g * 64 + f * 16 + lane15) * 32 + quad * 8];
      acc[f] = MFMA16(af, bf, acc[f]);
    }
    #pragma unroll
    for (int f = 0; f < 4; ++f)
      #pragma unroll
      for (int rr = 0; rr < 4; ++rr)
        WR[2 + w * 16 + quad * 4 + rr][g * 64 + f * 16 + lane15] = acc[f][rr];
  }
  LGKBAR();

  // ---- phase 3: conv(K=3) + SiLU + rotate + L2 normalize (fast transcendentals;
  //      outputs are bf16-rounded so ~21-bit intrinsics are within tolerance) ----
  {
    float cwa[3], cwb[3];
    #pragma unroll
    for (int i = 0; i < 3; ++i) {
      cwa[i] = conv_w[(long)(c0 + l) * 3 + i];
      cwb[i] = conv_w[(long)(c0 + 64 + l) * 3 + i];
    }
    float om = omega[r], ph = phi[r];
    for (int it = 0; it < 16; ++it) {
      int tl = it * 4 + w;
      int t = rm + tl;
      float a = cwa[0] * WR[tl][l] + cwa[1] * WR[tl + 1][l] + cwa[2] * WR[tl + 2][l];
      float b = cwb[0] * WR[tl][64 + l] + cwb[1] * WR[tl + 1][64 + l] + cwb[2] * WR[tl + 2][64 + l];
      a = a / (1.f + __expf(-a));
      b = b / (1.f + __expf(-b));
      float th = om * (float)t + ph;
      float wd = a * __cosf(th) + b * __sinf(th);
      float ss = wd * wd;
      #pragma unroll
      for (int o = 32; o > 0; o >>= 1) ss += __shfl_xor(ss, o, 64);
      ushort hv = f2b(wd * (1.f / sqrtf(ss + 1e-6f)));
      whb[((long)p * TTD + t) * HDIM + l] = hv;
      Wrow[tl * LS + l] = hv;
      WT[l * LS + tl] = hv;
    }
  }
  LGKBAR();   // WR reads done (Lm/Vf/Tb may overlay); Wrow/WT complete

  // ---- phase 4: solveA on this chunk ----
  const float* bet = beta + (long)p * TTD + rm;
  ushort* TBh = TB + ((long)p * 16 + c) * 4096;
  ushort* YBh = YB + ((long)p * 16 + c) * 4096;

  f32x4 g4[4] = {};
  #pragma unroll
  for (int s = 0; s < 2; ++s) {
    bf16x8 af = *(const bf16x8*)&Wrow[(w * 16 + lane15) * LS + s * 32 + quad * 8];
    #pragma unroll
    for (int f = 0; f < 4; ++f) {
      bf16x8 bf = *(const bf16x8*)&Wrow[(f * 16 + lane15) * LS + s * 32 + quad * 8];
      g4[f] = MFMA16(af, bf, g4[f]);
    }
  }
  #pragma unroll
  for (int r4 = 0; r4 < 4; ++r4) {
    int t = w * 16 + quad * 4 + r4;
    float bv = bet[t];
    #pragma unroll
    for (int f = 0; f < 4; ++f) {
      int tp = f * 16 + lane15;
      Lm[t][tp] = (t > tp) ? bv * g4[f][r4] : 0.f;
    }
  }
  LGKBAR();

  {
    float cur[16];
    #pragma unroll
    for (int i = 0; i < 16; ++i) cur[i] = (w * 16 + i == l) ? bet[l] : 0.f;
    for (int sb = 0; sb < 4; ++sb) {
      if (w == sb) {
        float xloc[16];
        #pragma unroll
        for (int i = 0; i < 16; ++i) {
          float bv = cur[i];
          #pragma unroll
          for (int j2 = 0; j2 < 16; ++j2)
            if (j2 < i) bv -= Lm[sb * 16 + i][sb * 16 + j2] * xloc[j2];
          xloc[i] = bv;
          Vf[sb * 16 + i][l] = bv;
        }
      }
      LGKBAR();
      if (w > sb) {
        float xp[16];
        #pragma unroll
        for (int t = 0; t < 16; ++t) xp[t] = Vf[sb * 16 + t][l];
        #pragma unroll
        for (int i = 0; i < 16; ++i) {
          float s2 = cur[i];
          #pragma unroll
          for (int t = 0; t < 16; ++t) s2 -= Lm[w * 16 + i][sb * 16 + t] * xp[t];
          cur[i] = s2;
        }
      }
    }
  }
  {
    int t = tid >> 2, off = (tid & 3) * 16;
    ushort tmp[16];
    #pragma unroll
    for (int i = 0; i < 16; ++i) { tmp[i] = f2b(Vf[t][off + i]); Tb[t * LS + off + i] = tmp[i]; }
    *(uint4*)&TBh[t * 64 + off] = *(const uint4*)&tmp[0];
    *(uint4*)&TBh[t * 64 + off + 8] = *(const uint4*)&tmp[8];
  }
  LGKBAR();
  f32x4 y[4] = {};
  #pragma unroll
  for (int s = 0; s < 2; ++s) {
    bf16x8 af = *(const bf16x8*)&Tb[(w * 16 + lane15) * LS + s * 32 + quad * 8];
    #pragma unroll
    for (int f = 0; f < 4; ++f) {
      bf16x8 bf = *(const bf16x8*)&WT[(f * 16 + lane15) * LS + s * 32 + quad * 8];
      y[f] = MFMA16(af, bf, y[f]);
    }
  }
  #pragma unroll
  for (int f = 0; f < 4; ++f)
    #pragma unroll
    for (int r4 = 0; r4 < 4; ++r4)
      YBh[(long)(w * 16 + quad * 4 + r4) * 64 + f * 16 + lane15] = f2b(y[f][r4]);
}

// ---------------- solveB: chunk recurrence; reg-prefetched whc/YB; SWZ2 WT ------------------
__global__ __launch_bounds__(256) void solveB_kernel(
    const ushort* __restrict__ whb, const ushort* __restrict__ kb,
    const ushort* __restrict__ TB, const ushort* __restrict__ YB,
    ushort* __restrict__ Xb, ushort* __restrict__ KZ)
{
  int h = blockIdx.x;
  int ty = blockIdx.y;
  int js = (ty < 8) ? ty : (23 - ty);
  int j0 = js * 64;
  const ushort* wh_h = whb + (long)h * TTD * HDIM;
  const ushort* k_h = kb + (long)(h >> 1) * 64;
  ushort* X_h = Xb + (long)h * XT_PERH;
  ushort* KZ_h = KZ + (long)h * 15 * TTD * HDIM;
  int xidx = js * 16 - js * (js - 1) / 2;   // packed tile index for (js, c=js)

  __shared__ ushort KT[4096];
  __shared__ ushort WT[4096];   // SWZ2-swizzled (transpose-write-friendly)
  __shared__ ushort XM[4096];
  __shared__ ushort nS[4096];

  int tid = threadIdx.x, w = tid >> 6, l = tid & 63;
  int quad = l >> 4, lane15 = l & 15;
  f32x4 Sacc[4] = {}, Wacc[4] = {};

  stage_tile(k_h + (long)j0 * DDM, DDM, KT, w, l);

  float kreg[4][4];
  #pragma unroll
  for (int f = 0; f < 4; ++f)
    #pragma unroll
    for (int r = 0; r < 4; ++r)
      kreg[f][r] = b2f(k_h[(long)(j0 + w * 16 + quad * 4 + r) * DDM + f * 16 + lane15]);

  // whc prefetch: thread covers rows {prow0, 32+prow0}, d-chunk pd0..pd0+7
  int prow0 = tid >> 3, pd0 = (tid & 7) * 8;
  uint4 pk0 = *(const uint4*)&wh_h[((long)js * 64 + prow0) * HDIM + pd0];
  uint4 pk1 = *(const uint4*)&wh_h[((long)js * 64 + 32 + prow0) * HDIM + pd0];
  bf16x8 ybr0 = {}, ybr1 = {};   // YB prefetch (valid from second iteration on)

  WAITVM(0);   // KT async stage landed

  for (int c = js; c < 16; ++c) {
    LGKBAR();
    // WT write from prefetched regs (conflict-free via SWZ2)
    {
      const ushort* pu0 = (const ushort*)&pk0;
      const ushort* pu1 = (const ushort*)&pk1;
      #pragma unroll
      for (int i = 0; i < 8; ++i) WT[SWZ2E(pd0 + i, prow0)] = pu0[i];
      #pragma unroll
      for (int i = 0; i < 8; ++i) WT[SWZ2E(pd0 + i, 32 + prow0)] = pu1[i];
    }
    // issue whc prefetch for c+1 (covered by this whole iteration)
    if (c < 15) {
      pk0 = *(const uint4*)&wh_h[((long)(c + 1) * 64 + prow0) * HDIM + pd0];
      pk1 = *(const uint4*)&wh_h[((long)(c + 1) * 64 + 32 + prow0) * HDIM + pd0];
    }
    f32x4 xacc[4] = {};
    if (c == js) {
      const ushort* whc = wh_h + (long)c * 64 * HDIM;
      f32x4 m[4] = {};
      #pragma unroll
      for (int s = 0; s < 2; ++s) {
        bf16x8 af = *(const bf16x8*)&whc[(long)(w * 16 + lane15) * HDIM + s * 32 + quad * 8];
        #pragma unroll
        for (int f = 0; f < 4; ++f)
          m[f] = MFMA16(af, frag(KT, f * 16 + lane15, s * 4 + quad), m[f]);
      }
      #pragma unroll
      for (int f = 0; f < 4; ++f)
        #pragma unroll
        for (int r = 0; r < 4; ++r) {
          int t = w * 16 + quad * 4 + r, j = f * 16 + lane15;
          XM[SWZE(j, t)] = (t > j) ? f2b(m[f][r]) : (ushort)0;
        }
      LGKBAR();
      const ushort* TBh = TB + ((long)h * 16 + c) * 4096;
      #pragma unroll
      for (int s = 0; s < 2; ++s) {
        bf16x8 af = *(const bf16x8*)&TBh[(long)(w * 16 + lane15) * 64 + s * 32 + quad * 8];
        #pragma unroll
        for (int f = 0; f < 4; ++f)
          xacc[f] = MFMA16(af, frag(XM, f * 16 + lane15, s * 4 + quad), xacc[f]);
      }
      LGKBAR();
    } else {
      // YB operand comes from registers prefetched last iteration
      #pragma unroll
      for (int f = 0; f < 4; ++f) {
        xacc[f] = MFMA16(ybr0, frag(KT, f * 16 + lane15, 0 * 4 + quad), xacc[f]);
        xacc[f] = MFMA16(ybr0, frag(nS, f * 16 + lane15, 0 * 4 + quad), xacc[f]);
        xacc[f] = MFMA16(ybr1, frag(KT, f * 16 + lane15, 1 * 4 + quad), xacc[f]);
        xacc[f] = MFMA16(ybr1, frag(nS, f * 16 + lane15, 1 * 4 + quad), xacc[f]);
      }
    }
    #pragma unroll
    for (int f = 0; f < 4; ++f)
      #pragma unroll
      for (int r = 0; r < 4; ++r)
        XM[SWZE(f * 16 + lane15, w * 16 + quad * 4 + r)] = f2b(xacc[f][r]);
    LGKBAR();
    {
      ushort* xt = X_h + (long)xidx * 4096;
      int j = tid >> 2, c2 = (tid & 3) * 2;
      bf16x8 s0 = frag(XM, j, c2);
      bf16x8 s1 = frag(XM, j, c2 + 1);
      *(bf16x8*)&xt[j * 64 + c2 * 8] = s0;
      *(bf16x8*)&xt[j * 64 + c2 * 8 + 8] = s1;
    }
    ++xidx;
    if (c < 15) {
      {
        const ushort* YBn = YB + ((long)h * 16 + c + 1) * 4096;
        ybr0 = *(const bf16x8*)&YBn[(long)(w * 16 + lane15) * 64 + 0 * 32 + quad * 8];
        ybr1 = *(const bf16x8*)&YBn[(long)(w * 16 + lane15) * 64 + 1 * 32 + quad * 8];
      }
      #pragma unroll
      for (int s = 0; s < 2; ++s) {
        bf16x8 aw = frag2(WT, w * 16 + lane15, s * 4 + quad);
        bf16x8 ax = frag(XM, w * 16 + lane15, s * 4 + quad);
        #pragma unroll
        for (int f = 0; f < 4; ++f) {
          Sacc[f] = MFMA16(aw, frag(XM, f * 16 + lane15, s * 4 + quad), Sacc[f]);
          Wacc[f] = MFMA16(ax, frag2(WT, f * 16 + lane15, s * 4 + quad), Wacc[f]);
        }
      }
      ushort* pz = KZ_h + (long)c * TTD * HDIM;
      #pragma unroll
      for (int f = 0; f < 4; ++f)
        #pragma unroll
        for (int r = 0; r < 4; ++r)
          pz[(long)(j0 + w * 16 + quad * 4 + r) * 64 + f * 16 + lane15] =
              f2b(kreg[f][r] - Wacc[f][r]);
      #pragma unroll
      for (int f = 0; f < 4; ++f)
        #pragma unroll
        for (int r = 0; r < 4; ++r)
          nS[SWZE(f * 16 + lane15, w * 16 + quad * 4 + r)] = f2b(-Sacc[f][r]);
    }
  }
}

// ---------------- flash: SINGLE-barrier dbuf pipeline, exp2 softmax + exact defer-max -------
__global__ __launch_bounds__(256) void flash_kernel(
    const ushort* __restrict__ qb, const ushort* __restrict__ kbuf,
    const ushort* __restrict__ whb, const ushort* __restrict__ Xb,
    const ushort* __restrict__ KZ, const ushort* __restrict__ vTb,
    ushort* __restrict__ oall)
{
  int h = blockIdx.x;
  int y = blockIdx.y;
  int ri = (y < 8) ? y : (23 - y);
  int r0 = ri * 64;
  const ushort* q_h = qb + (long)(h >> 1) * 64;
  const ushort* k_h = kbuf + (long)(h >> 1) * 64;
  const ushort* wh_h = whb + (long)h * TTD * HDIM;
  const ushort* X_h = Xb + (long)h * XT_PERH;
  const ushort* kz = KZ + ((long)h * 15 + (ri - 1)) * TTD * HDIM;
  const ushort* v_h = vTb + (long)(h >> 1) * 64 * TTD;

  __shared__ ushort S[2][3][4096];
  __shared__ ushort KD[4096];
  __shared__ ushort QWD[4096];
  __shared__ ushort PT[4096];

  int tid = threadIdx.x, w = tid >> 6, l = tid & 63;
  int quad = l >> 4, lane15 = l & 15;

  bf16x8 aq[2];
  #pragma unroll
  for (int s = 0; s < 2; ++s)
    aq[s] = *(const bf16x8*)&q_h[(long)(r0 + w * 16 + lane15) * DDM + s * 32 + quad * 8];
  // KD + jb=0 tiles staged early; QWD (wave-private rows 16w..16w+15) while loads fly
  const ushort* xst = X_h + (long)ri * 4096;   // packed tile (0, ri)
  stage_tile(k_h + (long)r0 * DDM, DDM, KD, w, l);
  if (ri > 0) stage_tile(kz, 64, &S[0][0][0], w, l);
  stage_tile(xst, 64, &S[0][1][0], w, l);
  stage_tile(v_h, TTD, &S[0][2][0], w, l);
  {
    f32x4 t4[4] = {};
    #pragma unroll
    for (int s = 0; s < 2; ++s)
      #pragma unroll
      for (int f = 0; f < 4; ++f) {
        bf16x8 bf = *(const bf16x8*)&wh_h[(long)(r0 + f * 16 + lane15) * HDIM + s * 32 + quad * 8];
        t4[f] = MFMA16(aq[s], bf, t4[f]);
      }
    #pragma unroll
    for (int f = 0; f < 4; ++f)
      #pragma unroll
      for (int r = 0; r < 4; ++r) {
        int i = w * 16 + quad * 4 + r, t = f * 16 + lane15;
        QWD[SWZE(i, t)] = (i >= t) ? f2b(-t4[f][r]) : (ushort)0;
      }
  }

  f32x4 O[4] = {};
  float m[4], lsum[4];
  #pragma unroll
  for (int r = 0; r < 4; ++r) { m[r] = -1e30f; lsum[r] = 0.f; }

  for (int jb = 0; jb <= ri; ++jb) {
    int cur = jb & 1;
    const ushort* xnx = xst + (long)(15 - jb) * 4096;  // packed tile (jb+1, ri)
    WAITVM(0);     // own prev-iteration loads landed (full compute phase of cover)
    BAR();         // joins waves; frees S[cur^1] (read last iteration)
    if (jb < ri) {
      long c0n = (long)(jb + 1) * 64;
      ushort* nb = &S[cur ^ 1][0][0];
      if (jb + 1 < ri) stage_tile(kz + c0n * 64, 64, nb, w, l);
      stage_tile(xnx, 64, nb + 4096, w, l);
      stage_tile(v_h + c0n, TTD, nb + 8192, w, l);
    }
    const ushort* Skz = &S[cur][0][0];
    const ushort* Sx  = &S[cur][1][0];
    const ushort* Sv  = &S[cur][2][0];
    f32x4 acc[4] = {};
    const ushort* Sb = (jb < ri) ? Skz : KD;
    #pragma unroll
    for (int s = 0; s < 2; ++s)
      #pragma unroll
      for (int f = 0; f < 4; ++f)
        acc[f] = MFMA16(aq[s], frag(Sb, f * 16 + lane15, s * 4 + quad), acc[f]);
    #pragma unroll
    for (int s = 0; s < 2; ++s) {
      bf16x8 aw = frag(QWD, w * 16 + lane15, s * 4 + quad);
      #pragma unroll
      for (int f = 0; f < 4; ++f)
        acc[f] = MFMA16(aw, frag(Sx, f * 16 + lane15, s * 4 + quad), acc[f]);
    }
    float rmax[4] = {-3e38f, -3e38f, -3e38f, -3e38f};
    #pragma unroll
    for (int f = 0; f < 4; ++f)
      #pragma unroll
      for (int r = 0; r < 4; ++r) {
        float lv = acc[f][r] * PSC2;       // exp2 domain
        if (jb == ri && (f * 16 + lane15) > (w * 16 + quad * 4 + r)) lv = -3e38f;
        acc[f][r] = lv;
        rmax[r] = fmaxf(rmax[r], lv);
      }
    #pragma unroll
    for (int r = 0; r < 4; ++r) {
      rmax[r] = fmaxf(rmax[r], __shfl_xor(rmax[r], 1, 64));
      rmax[r] = fmaxf(rmax[r], __shfl_xor(rmax[r], 2, 64));
      rmax[r] = fmaxf(rmax[r], __shfl_xor(rmax[r], 4, 64));
      rmax[r] = fmaxf(rmax[r], __shfl_xor(rmax[r], 8, 64));
    }
    // exact defer-max: when no row's max grew (wave-wide), the rescale is identity
    bool grow = (rmax[0] > m[0]) | (rmax[1] > m[1]) | (rmax[2] > m[2]) | (rmax[3] > m[3]);
    if (__any(grow)) {
      float alpha[4];
      #pragma unroll
      for (int r = 0; r < 4; ++r) {
        float nm = fmaxf(m[r], rmax[r]);
        alpha[r] = exp2f(m[r] - nm);
        m[r] = nm;
        lsum[r] *= alpha[r];
      }
      #pragma unroll
      for (int f = 0; f < 4; ++f)
        #pragma unroll
        for (int r = 0; r < 4; ++r) O[f][r] *= alpha[r];
    }
    float rs[4] = {0.f, 0.f, 0.f, 0.f};
    #pragma unroll
    for (int f = 0; f < 4; ++f)
      #pragma unroll
      for (int r = 0; r < 4; ++r) {
        float e = exp2f(acc[f][r] - m[r]);
        acc[f][r] = e;
        rs[r] += e;
      }
    #pragma unroll
    for (int r = 0; r < 4; ++r) {
      rs[r] += __shfl_xor(rs[r], 1, 64);
      rs[r] += __shfl_xor(rs[r], 2, 64);
      rs[r] += __shfl_xor(rs[r], 4, 64);
      rs[r] += __shfl_xor(rs[r], 8, 64);
      lsum[r] += rs[r];
    }
    #pragma unroll
    for (int f = 0; f < 4; ++f)
      #pragma unroll
      for (int r = 0; r < 4; ++r) {
        int i = w * 16 + quad * 4 + r;
        PT[SWZE(i, f * 16 + lane15)] = f2b(acc[f][r]);
      }
    // PT is wave-private: lgkmcnt orders ds_write -> ds_read within the wave
    #pragma unroll
    for (int s = 0; s < 2; ++s) {
      bf16x8 ap = frag(PT, w * 16 + lane15, s * 4 + quad);
      #pragma unroll
      for (int f = 0; f < 4; ++f)
        O[f] = MFMA16(ap, frag(Sv, f * 16 + lane15, s * 4 + quad), O[f]);
    }
    xst = xnx;
  }
  #pragma unroll
  for (int r = 0; r < 4; ++r) lsum[r] = 1.f / lsum[r];
  #pragma unroll
  for (int f = 0; f < 4; ++f)
    #pragma unroll
    for (int r = 0; r < 4; ++r)
      oall[(long)(r0 + w * 16 + quad * 4 + r) * 2048 + h * 64 + f * 16 + lane15] =
          f2b(O[f][r] * lsum[r]);
}

// ---------------- final GEMM: out = o_all(bf16) @ ow_b^T (single-barrier dbuf, BK=128) ------
__global__ __launch_bounds__(256) void gemm_out_kernel(
    const ushort* __restrict__ A, const ushort* __restrict__ Bb, float* __restrict__ C)
{
  __shared__ ushort Ab[2][8192];
  __shared__ ushort Bt[2][8192];
  int tid = threadIdx.x, w = tid >> 6, l = tid & 63;
  int quad = l >> 4, lane15 = l & 15;
  int rm = blockIdx.y * 64, cn = blockIdx.x * 64;
  const ushort* Ag = A + (long)rm * 2048;
  const ushort* Bg = Bb + (long)cn * 2048;

  stage_tile(Ag, 2048, &Ab[0][0], w, l);
  stage_tile(Ag + 64, 2048, &Ab[0][4096], w, l);
  stage_tile(Bg, 2048, &Bt[0][0], w, l);
  stage_tile(Bg + 64, 2048, &Bt[0][4096], w, l);

  f32x4 acc[4] = {};
  for (int kt = 0; kt < 16; ++kt) {
    int cur = kt & 1;
    WAITVM(0);
    BAR();
    if (kt < 15) {
      int nxt = cur ^ 1;
      long o = (long)(kt + 1) * 128;
      stage_tile(Ag + o, 2048, &Ab[nxt][0], w, l);
      stage_tile(Ag + o + 64, 2048, &Ab[nxt][4096], w, l);
      stage_tile(Bg + o, 2048, &Bt[nxt][0], w, l);
      stage_tile(Bg + o + 64, 2048, &Bt[nxt][4096], w, l);
    }
    #pragma unroll
    for (int u = 0; u < 2; ++u)
      #pragma unroll
      for (int s = 0; s < 2; ++s) {
        bf16x8 af = frag(&Ab[cur][u * 4096], w * 16 + lane15, s * 4 + quad);
        #pragma unroll
        for (int f = 0; f < 4; ++f)
          acc[f] = MFMA16(af, frag(&Bt[cur][u * 4096], f * 16 + lane15, s * 4 + quad), acc[f]);
      }
  }
  int orow = rm + w * 16 + quad * 4;
  #pragma unroll
  for (int f = 0; f < 4; ++f)
    #pragma unroll
    for (int r = 0; r < 4; ++r)
      C[(long)(orow + r) * DDM + cn + f * 16 + lane15] = acc[f][r];
}

// ---------------- host ----------------
extern "C" void kernel_launch(void* const* d_in, const int* in_sizes, int n_in,
                              void* d_out, int out_size, void* d_ws, size_t ws_size,
                              hipStream_t stream) {
  const float* hs     = (const float*)d_in[0];
  const float* q_w    = (const float*)d_in[1];
  const float* k_w    = (const float*)d_in[2];
  const float* v_w    = (const float*)d_in[3];
  const float* w1     = (const float*)d_in[4];
  const float* w2     = (const float*)d_in[5];
  const float* conv_w = (const float*)d_in[6];
  const float* bt_w   = (const float*)d_in[7];
  const float* bt_b   = (const float*)d_in[8];
  const float* o_w    = (const float*)d_in[9];
  const float* omega  = (const float*)d_in[10];
  const float* phi    = (const float*)d_in[11];
  float* out = (float*)d_out;
  char* ws = (char*)d_ws;

  ushort* Xb     = (ushort*)(ws + OFF_X);
  ushort* KZb    = (ushort*)(ws + OFF_PZ);
  ushort* hs_b   = (ushort*)(ws + OFF_HSB);
  ushort* qw_wb  = (ushort*)(ws + OFF_QWW);
  ushort* kw_wb  = (ushort*)(ws + OFF_KWW);
  ushort* vw_wb  = (ushort*)(ws + OFF_VWW);
  ushort* w2_b   = (ushort*)(ws + OFF_W2B);
  ushort* wlow_b = (ushort*)(ws + OFF_WLOWB);
  ushort* TB     = (ushort*)(ws + OFF_TB);
  ushort* o_all  = (ushort*)(ws + OFF_OALL);
  ushort* YB     = (ushort*)(ws + OFF_YB);
  ushort* ow_b   = (ushort*)(ws + OFF_OWB);
  ushort* wh_b   = (ushort*)(ws + OFF_WHB);
  ushort* q_b    = (ushort*)(ws + OFF_QB);
  ushort* k_b    = (ushort*)(ws + OFF_KB);
  ushort* vT_b   = (ushort*)(ws + OFF_VTB);
  float*  beta   = (float*)(ws + OFF_BETA);
  ushort* bw_b   = (ushort*)(ws + OFF_BW64);

  CvtSegs sg;
  sg.src[0] = hs;   sg.dst[0] = hs_b;          sg.cnt[0] = 1048576;
  sg.src[1] = q_w;  sg.dst[1] = qw_wb;         sg.cnt[1] = 1048576;
  sg.src[2] = k_w;  sg.dst[2] = kw_wb;         sg.cnt[2] = 1048576;
  sg.src[3] = v_w;  sg.dst[3] = vw_wb;         sg.cnt[3] = 1048576;
  sg.src[4] = w2;   sg.dst[4] = w2_b;          sg.cnt[4] = 131072;
  sg.src[5] = bt_w; sg.dst[5] = bw_b;          sg.cnt[5] = 32768;
  sg.src[6] = w1;   sg.dst[6] = bw_b + 32768;  sg.cnt[6] = 32768;
  sg.src[7] = o_w;  sg.dst[7] = ow_b;          sg.cnt[7] = 2097152;
  cvt_all_kernel<<<dim3((CVT_TOTAL + 1023) / 1024), 256, 0, stream>>>(sg);

  qkv_sp_kernel<<<dim3(16, 8, 4), 256, 0, stream>>>(
      hs_b, qw_wb, kw_wb, vw_wb, bw_b, bt_b, q_b, k_b, vT_b, beta, wlow_b);

  wraw_solveA_kernel<<<dim3(16, 32), 256, 0, stream>>>(
      wlow_b, w2_b, conv_w, omega, phi, beta, wh_b, TB, YB);

  solveB_kernel<<<dim3(32, 16), 256, 0, stream>>>(wh_b, k_b, TB, YB, Xb, KZb);

  flash_kernel<<<dim3(32, 16), 256, 0, stream>>>(q_b, k_b, wh_b, Xb, KZb, vT_b, o_all);

  gemm_out_kernel<<<dim3(16, 16), 256, 0, stream>>>(o_all, ow_b, out);

  (void)in_sizes; (void)n_in; (void)out_size; (void)ws_size;
}

// Round 7
// 209.643 us; speedup vs baseline: 1.0486x; 1.0486x over previous
//
#include <hip/hip_runtime.h>
#include <math.h>

// ---------------- problem constants ----------------
#define TTD 1024
#define DDM 1024
#define HDIM 64
#define PSCALE 0.125f
// PSCALE * log2(e): flash softmax runs in exp2 domain
#define PSC2 0.18033688011112042f
#define LS 72   // padded LDS stride (wraw_solveA)

typedef __attribute__((ext_vector_type(8))) __bf16 bf16x8;
typedef __attribute__((ext_vector_type(4))) float f32x4;
#define MFMA16(a,b,c) __builtin_amdgcn_mfma_f32_16x16x32_bf16(a,b,c,0,0,0)

// counted vmcnt wait + raw barriers (prefetch is ALWAYS issued before the wait point)
#define STR_(x) #x
#define WAITVM(N) asm volatile("s_waitcnt vmcnt(" STR_(N) ")" ::: "memory")
#define BAR() do { __builtin_amdgcn_s_barrier(); asm volatile("" ::: "memory"); } while (0)
#define LGKBAR() do { asm volatile("s_waitcnt lgkmcnt(0)" ::: "memory"); \
                      __builtin_amdgcn_s_barrier(); asm volatile("" ::: "memory"); } while (0)
#define FULLBAR() do { asm volatile("s_waitcnt vmcnt(0) lgkmcnt(0)" ::: "memory"); \
                       __builtin_amdgcn_s_barrier(); asm volatile("" ::: "memory"); } while (0)

__device__ __forceinline__ ushort f2b(float f) {
  unsigned u = __builtin_bit_cast(unsigned, f);
  return (ushort)((u + 0x7fffu + ((u >> 16) & 1u)) >> 16);
}
__device__ __forceinline__ float b2f(ushort u) {
  unsigned v = (unsigned)u << 16;
  return __builtin_bit_cast(float, v);
}

__device__ __forceinline__ void gload_lds16(const ushort* g, ushort* l) {
  __builtin_amdgcn_global_load_lds(
      (const __attribute__((address_space(1))) unsigned*)g,
      (__attribute__((address_space(3))) unsigned*)l, 16, 0, 0);
}

// XOR-swizzled 64x64 bf16 tile: 16B slot index for (row, chunk)
#define SWZ(row, cc) (((row) * 8 + ((cc) ^ ((row) & 7))) * 8)
#define SWZE(row, col) (SWZ(row, (col) >> 3) + ((col) & 7))
// transpose-write-friendly swizzle (solveB WT only): key = (row&7)^(row>>3).
#define SWZ2(row, cc) (((row) * 8 + ((cc) ^ (((row) & 7) ^ ((row) >> 3)))) * 8)
#define SWZ2E(row, col) (SWZ2(row, (col) >> 3) + ((col) & 7))

// async-stage one 64x64 tile (rows at gs-elem stride) into swizzled LDS tile
// issues exactly 2 global_load_lds instructions per thread
__device__ __forceinline__ void stage_tile(const ushort* gb, long gs, ushort* tile,
                                           int w, int l) {
  int sub = l >> 3, cc = (l & 7) ^ sub;
  #pragma unroll
  for (int it = 0; it < 2; ++it) {
    int q = w * 2 + it;
    gload_lds16(gb + (long)(q * 8 + sub) * gs + cc * 8, &tile[(q * 64 + l) * 8]);
  }
}

__device__ __forceinline__ bf16x8 frag(const ushort* tile, int row, int cc) {
  return *(const bf16x8*)&tile[SWZ(row, cc)];
}
__device__ __forceinline__ bf16x8 frag2(const ushort* tile, int row, int cc) {
  return *(const bf16x8*)&tile[SWZ2(row, cc)];
}

// ---------------- workspace layout (bytes); total used = 121,896,960 ----------
#define XT_PERH   557056L       // packed-UT X elems per head (136*4096)
#define OFF_X     0L            // 35,651,584 B
#define OFF_PZ    35651584L     // KZ bf16 [32][15][1024 j][64 d] : 60 MiB
// aliases inside KZ region (all dead before solveB writes KZ):
#define OFF_HSB   35651584L
#define OFF_QWW   37748736L
#define OFF_KWW   39845888L
#define OFF_VWW   41943040L
#define OFF_W2B   44040192L
#define OFF_WLOWB 44302336L
#define OFF_TB    98566144L     // Tbeta bf16 (wraw_solveA->solveB); dead after solveB
#define OFF_OALL  98566144L     // o_all overlays TB (flash writes after solveB)
#define OFF_YB    102760448L    // Yb bf16 (wraw_solveA->solveB)
#define OFF_OWB   106954752L    // ow_b own region: converted at t=0 by cvt_all
#define OFF_WHB   111149056L    // wh bf16 (live through flash)
#define OFF_QB    115343360L
#define OFF_KB    117440512L
#define OFF_VTB   119537664L
#define OFF_BETA  121634816L
#define OFF_BW64  121765888L    // 64x1024 bf16 [bt_w ; w1]

// ---------------- merged fp32 -> bf16 convert (8 segments, one launch) ----------------
#define CVT_TOTAL 6488064L
struct CvtSegs {
  const float* src[8];
  ushort* dst[8];
  long cnt[8];
};
__global__ __launch_bounds__(256) void cvt_all_kernel(CvtSegs sg) {
  long e = ((long)blockIdx.x * 256 + threadIdx.x) * 4;
  #pragma unroll
  for (int s = 0; s < 8; ++s) {
    if (e < sg.cnt[s]) {
      float4 f = *(const float4*)(sg.src[s] + e);
      ushort4 o;
      o.x = f2b(f.x); o.y = f2b(f.y); o.z = f2b(f.z); o.w = f2b(f.w);
      *(ushort4*)(sg.dst[s] + e) = o;
      return;
    }
    e -= sg.cnt[s];
  }
}

// ---------------- fused QKV + small projections: z in {Q,K,V, small} ----------------
// BM=128 x BN=64; counted-vmcnt dbuf: {stage next; WAITVM(6); BAR; compute; BAR}
// (prefetch issued BEFORE the wait point -> loads in flight across barrier+compute)
__global__ __launch_bounds__(256) void qkv_sp_kernel(
    const ushort* __restrict__ hsb,
    const ushort* __restrict__ wq, const ushort* __restrict__ wk, const ushort* __restrict__ wv,
    const ushort* __restrict__ bw, const float* __restrict__ bt_b,
    ushort* __restrict__ cq, ushort* __restrict__ ck, ushort* __restrict__ cv,
    float* __restrict__ beta, ushort* __restrict__ wlowb)
{
  int z = blockIdx.z;
  if (z == 3 && blockIdx.x != 0) return;
  const ushort* B = (z == 0) ? wq : (z == 1) ? wk : (z == 2) ? wv : bw;

  __shared__ ushort Ab[2][8192];   // two stacked swizzled 64x64 tiles (128 rows)
  __shared__ ushort Bb[2][4096];

  int tid = threadIdx.x, w = tid >> 6, l = tid & 63;
  int quad = l >> 4, lane15 = l & 15;
  int rm = blockIdx.y * 128, cn = (z == 3) ? 0 : blockIdx.x * 64;
  const ushort* Ag = hsb + (long)rm * DDM;
  const ushort* Bg = B + (long)cn * DDM;

  // prologue: stage tile 0 (6 vm insts)
  stage_tile(Ag, DDM, &Ab[0][0], w, l);
  stage_tile(Ag + 64 * DDM, DDM, &Ab[0][4096], w, l);
  stage_tile(Bg, DDM, &Bb[0][0], w, l);

  f32x4 acc[2][4] = {};
  int arow0 = (w & 1) * 32 + lane15;
  int asel = (w >> 1) * 4096;
  for (int kt = 0; kt < 16; ++kt) {
    int cur = kt & 1;
    if (kt < 15) {
      int nxt = cur ^ 1;
      stage_tile(Ag + (kt + 1) * 64, DDM, &Ab[nxt][0], w, l);
      stage_tile(Ag + 64 * DDM + (kt + 1) * 64, DDM, &Ab[nxt][4096], w, l);
      stage_tile(Bg + (kt + 1) * 64, DDM, &Bb[nxt][0], w, l);
      WAITVM(6);       // tile kt retired; tile kt+1's 6 loads stay in flight
    } else {
      WAITVM(0);
    }
    BAR();
    const ushort* Atile = &Ab[cur][asel];
    #pragma unroll
    for (int s = 0; s < 2; ++s) {
      bf16x8 a0 = frag(Atile, arow0, s * 4 + quad);
      bf16x8 a1 = frag(Atile, arow0 + 16, s * 4 + quad);
      #pragma unroll
      for (int f = 0; f < 4; ++f) {
        bf16x8 bf = frag(&Bb[cur][0], f * 16 + lane15, s * 4 + quad);
        acc[0][f] = MFMA16(a0, bf, acc[0][f]);
        acc[1][f] = MFMA16(a1, bf, acc[1][f]);
      }
    }
    BAR();             // readers done -> next iter may overwrite the other buffer
  }

  if (z < 2) {
    ushort* Cb = (z == 0) ? cq : ck;
    #pragma unroll
    for (int rr = 0; rr < 2; ++rr) {
      int orow = rm + w * 32 + rr * 16 + quad * 4;
      #pragma unroll
      for (int f = 0; f < 4; ++f)
        #pragma unroll
        for (int r = 0; r < 4; ++r)
          Cb[(long)(orow + r) * DDM + cn + f * 16 + lane15] = f2b(acc[rr][f][r]);
    }
  } else if (z == 2) {
    #pragma unroll
    for (int rr = 0; rr < 2; ++rr) {
      int orow = rm + w * 32 + rr * 16 + quad * 4;
      #pragma unroll
      for (int f = 0; f < 4; ++f) {
        ushort4 o;
        o.x = f2b(acc[rr][f][0]); o.y = f2b(acc[rr][f][1]);
        o.z = f2b(acc[rr][f][2]); o.w = f2b(acc[rr][f][3]);
        *(ushort4*)&cv[(long)(cn + f * 16 + lane15) * TTD + orow] = o;
      }
    }
  } else {
    #pragma unroll
    for (int rr = 0; rr < 2; ++rr) {
      int orow = rm + w * 32 + rr * 16 + quad * 4;
      #pragma unroll
      for (int f = 0; f < 2; ++f) {
        int hr = f * 16 + lane15;
        float bb = bt_b[hr];
        #pragma unroll
        for (int r = 0; r < 4; ++r)
          beta[(long)hr * TTD + orow + r] = 2.f / (1.f + __expf(-(acc[rr][f][r] + bb)));
      }
      #pragma unroll
      for (int f = 2; f < 4; ++f)
        #pragma unroll
        for (int r = 0; r < 4; ++r)
          wlowb[(long)(orow + r) * 32 + (f - 2) * 16 + lane15] = f2b(acc[rr][f][r]);
    }
  }
}

// ---------------- FUSED: w_raw GEMM + conv + SiLU + rotate + normalize + solveA -------------
__global__ __launch_bounds__(256) void wraw_solveA_kernel(
    const ushort* __restrict__ wlowb, const ushort* __restrict__ w2b,
    const float* __restrict__ conv_w, const float* __restrict__ omega,
    const float* __restrict__ phi, const float* __restrict__ beta,
    ushort* __restrict__ whb, ushort* __restrict__ TB, ushort* __restrict__ YB)
{
  int c = blockIdx.x;
  int rm = c * 64;
  int p = blockIdx.y;             // head hr
  int hkv = p >> 1, r = p & 1;
  int c0 = hkv * 256 + r * 128;

  __shared__ char pool_[65568];
  ushort* As = (ushort*)pool_;
  ushort* Bs = (ushort*)(pool_ + 4096);
  float (*WR)[132] = (float(*)[132])(pool_ + 12288);
  ushort* Wrow = (ushort*)(pool_ + 47136);   // wh row-major [t][d], stride LS
  ushort* WT   = (ushort*)(pool_ + 56352);   // wh transposed [d][t], stride LS
  float (*Lm)[65] = (float(*)[65])pool_;
  float (*Vf)[65] = (float(*)[65])(pool_ + 16640);
  ushort* Tb = (ushort*)(pool_ + 33280);

  int tid = threadIdx.x, w = tid >> 6, l = tid & 63;
  int quad = l >> 4, lane15 = l & 15;

  // ---- phase 1: async-stage A (w_low rows) + B (w2 rows, 128) ----
  {
    int row = tid >> 2, ch = (tid & 3) * 8;
    gload_lds16(wlowb + (long)(rm + row) * 32 + ch, &As[row * 32 + ch]);
    gload_lds16(w2b + (long)(c0 + row) * 32 + ch, &Bs[row * 32 + ch]);
    gload_lds16(w2b + (long)(c0 + 64 + row) * 32 + ch, &Bs[(64 + row) * 32 + ch]);
  }
  // halo rows rm-2, rm-1 (VALU dot; zero when rm==0 -> causal pad)
  {
    int hr2 = tid >> 7, col = tid & 127;
    float acc = 0.f;
    if (rm > 0) {
      long t = rm - 2 + hr2;
      for (int k = 0; k < 32; ++k)
        acc += b2f(wlowb[t * 32 + k]) * b2f(w2b[(long)(c0 + col) * 32 + k]);
    }
    WR[hr2][col] = acc;
  }
  FULLBAR();   // async stage consumed next

  // ---- phase 2: main 64x128 GEMM via MFMA (two 64-col halves) ----
  #pragma unroll
  for (int g = 0; g < 2; ++g) {
    f32x4 acc[4] = {};
    bf16x8 af = *(const bf16x8*)&As[(w * 16 + lane15) * 32 + quad * 8];
    #pragma unroll
    for (int f = 0; f < 4; ++f) {
      bf16x8 bf = *(const bf16x8*)&Bs[(g * 64 + f * 16 + lane15) * 32 + quad * 8];
      acc[f] = MFMA16(af, bf, acc[f]);
    }
    #pragma unroll
    for (int f = 0; f < 4; ++f)
      #pragma unroll
      for (int rr = 0; rr < 4; ++rr)
        WR[2 + w * 16 + quad * 4 + rr][g * 64 + f * 16 + lane15] = acc[f][rr];
  }
  LGKBAR();

  // ---- phase 3: conv(K=3) + SiLU + rotate + L2 normalize (fast transcendentals;
  //      outputs are bf16-rounded so ~21-bit intrinsics are within tolerance) ----
  {
    float cwa[3], cwb[3];
    #pragma unroll
    for (int i = 0; i < 3; ++i) {
      cwa[i] = conv_w[(long)(c0 + l) * 3 + i];
      cwb[i] = conv_w[(long)(c0 + 64 + l) * 3 + i];
    }
    float om = omega[r], ph = phi[r];
    for (int it = 0; it < 16; ++it) {
      int tl = it * 4 + w;
      int t = rm + tl;
      float a = cwa[0] * WR[tl][l] + cwa[1] * WR[tl + 1][l] + cwa[2] * WR[tl + 2][l];
      float b = cwb[0] * WR[tl][64 + l] + cwb[1] * WR[tl + 1][64 + l] + cwb[2] * WR[tl + 2][64 + l];
      a = a / (1.f + __expf(-a));
      b = b / (1.f + __expf(-b));
      float th = om * (float)t + ph;
      float wd = a * __cosf(th) + b * __sinf(th);
      float ss = wd * wd;
      #pragma unroll
      for (int o = 32; o > 0; o >>= 1) ss += __shfl_xor(ss, o, 64);
      ushort hv = f2b(wd * (1.f / sqrtf(ss + 1e-6f)));
      whb[((long)p * TTD + t) * HDIM + l] = hv;
      Wrow[tl * LS + l] = hv;
      WT[l * LS + tl] = hv;
    }
  }
  LGKBAR();   // WR reads done (Lm/Vf/Tb may overlay); Wrow/WT complete

  // ---- phase 4: solveA on this chunk ----
  const float* bet = beta + (long)p * TTD + rm;
  ushort* TBh = TB + ((long)p * 16 + c) * 4096;
  ushort* YBh = YB + ((long)p * 16 + c) * 4096;

  f32x4 g4[4] = {};
  #pragma unroll
  for (int s = 0; s < 2; ++s) {
    bf16x8 af = *(const bf16x8*)&Wrow[(w * 16 + lane15) * LS + s * 32 + quad * 8];
    #pragma unroll
    for (int f = 0; f < 4; ++f) {
      bf16x8 bf = *(const bf16x8*)&Wrow[(f * 16 + lane15) * LS + s * 32 + quad * 8];
      g4[f] = MFMA16(af, bf, g4[f]);
    }
  }
  #pragma unroll
  for (int r4 = 0; r4 < 4; ++r4) {
    int t = w * 16 + quad * 4 + r4;
    float bv = bet[t];
    #pragma unroll
    for (int f = 0; f < 4; ++f) {
      int tp = f * 16 + lane15;
      Lm[t][tp] = (t > tp) ? bv * g4[f][r4] : 0.f;
    }
  }
  LGKBAR();

  {
    float cur[16];
    #pragma unroll
    for (int i = 0; i < 16; ++i) cur[i] = (w * 16 + i == l) ? bet[l] : 0.f;
    for (int sb = 0; sb < 4; ++sb) {
      if (w == sb) {
        float xloc[16];
        #pragma unroll
        for (int i = 0; i < 16; ++i) {
          float bv = cur[i];
          #pragma unroll
          for (int j2 = 0; j2 < 16; ++j2)
            if (j2 < i) bv -= Lm[sb * 16 + i][sb * 16 + j2] * xloc[j2];
          xloc[i] = bv;
          Vf[sb * 16 + i][l] = bv;
        }
      }
      LGKBAR();
      if (w > sb) {
        float xp[16];
        #pragma unroll
        for (int t = 0; t < 16; ++t) xp[t] = Vf[sb * 16 + t][l];
        #pragma unroll
        for (int i = 0; i < 16; ++i) {
          float s2 = cur[i];
          #pragma unroll
          for (int t = 0; t < 16; ++t) s2 -= Lm[w * 16 + i][sb * 16 + t] * xp[t];
          cur[i] = s2;
        }
      }
    }
  }
  {
    int t = tid >> 2, off = (tid & 3) * 16;
    ushort tmp[16];
    #pragma unroll
    for (int i = 0; i < 16; ++i) { tmp[i] = f2b(Vf[t][off + i]); Tb[t * LS + off + i] = tmp[i]; }
    *(uint4*)&TBh[t * 64 + off] = *(const uint4*)&tmp[0];
    *(uint4*)&TBh[t * 64 + off + 8] = *(const uint4*)&tmp[8];
  }
  LGKBAR();
  f32x4 y[4] = {};
  #pragma unroll
  for (int s = 0; s < 2; ++s) {
    bf16x8 af = *(const bf16x8*)&Tb[(w * 16 + lane15) * LS + s * 32 + quad * 8];
    #pragma unroll
    for (int f = 0; f < 4; ++f) {
      bf16x8 bf = *(const bf16x8*)&WT[(f * 16 + lane15) * LS + s * 32 + quad * 8];
      y[f] = MFMA16(af, bf, y[f]);
    }
  }
  #pragma unroll
  for (int f = 0; f < 4; ++f)
    #pragma unroll
    for (int r4 = 0; r4 < 4; ++r4)
      YBh[(long)(w * 16 + quad * 4 + r4) * 64 + f * 16 + lane15] = f2b(y[f][r4]);
}

// ---------------- solveB: chunk recurrence; reg-prefetched whc/YB; SWZ2 WT ------------------
__global__ __launch_bounds__(256) void solveB_kernel(
    const ushort* __restrict__ whb, const ushort* __restrict__ kb,
    const ushort* __restrict__ TB, const ushort* __restrict__ YB,
    ushort* __restrict__ Xb, ushort* __restrict__ KZ)
{
  int h = blockIdx.x;
  int ty = blockIdx.y;
  int js = (ty < 8) ? ty : (23 - ty);
  int j0 = js * 64;
  const ushort* wh_h = whb + (long)h * TTD * HDIM;
  const ushort* k_h = kb + (long)(h >> 1) * 64;
  ushort* X_h = Xb + (long)h * XT_PERH;
  ushort* KZ_h = KZ + (long)h * 15 * TTD * HDIM;
  int xidx = js * 16 - js * (js - 1) / 2;   // packed tile index for (js, c=js)

  __shared__ ushort KT[4096];
  __shared__ ushort WT[4096];   // SWZ2-swizzled (transpose-write-friendly)
  __shared__ ushort XM[4096];
  __shared__ ushort nS[4096];

  int tid = threadIdx.x, w = tid >> 6, l = tid & 63;
  int quad = l >> 4, lane15 = l & 15;
  f32x4 Sacc[4] = {}, Wacc[4] = {};

  stage_tile(k_h + (long)j0 * DDM, DDM, KT, w, l);

  float kreg[4][4];
  #pragma unroll
  for (int f = 0; f < 4; ++f)
    #pragma unroll
    for (int r = 0; r < 4; ++r)
      kreg[f][r] = b2f(k_h[(long)(j0 + w * 16 + quad * 4 + r) * DDM + f * 16 + lane15]);

  // whc prefetch: thread covers rows {prow0, 32+prow0}, d-chunk pd0..pd0+7
  int prow0 = tid >> 3, pd0 = (tid & 7) * 8;
  uint4 pk0 = *(const uint4*)&wh_h[((long)js * 64 + prow0) * HDIM + pd0];
  uint4 pk1 = *(const uint4*)&wh_h[((long)js * 64 + 32 + prow0) * HDIM + pd0];
  bf16x8 ybr0 = {}, ybr1 = {};   // YB prefetch (valid from second iteration on)

  WAITVM(0);   // KT async stage landed

  for (int c = js; c < 16; ++c) {
    LGKBAR();
    // WT write from prefetched regs (conflict-free via SWZ2)
    {
      const ushort* pu0 = (const ushort*)&pk0;
      const ushort* pu1 = (const ushort*)&pk1;
      #pragma unroll
      for (int i = 0; i < 8; ++i) WT[SWZ2E(pd0 + i, prow0)] = pu0[i];
      #pragma unroll
      for (int i = 0; i < 8; ++i) WT[SWZ2E(pd0 + i, 32 + prow0)] = pu1[i];
    }
    // issue whc prefetch for c+1 (covered by this whole iteration)
    if (c < 15) {
      pk0 = *(const uint4*)&wh_h[((long)(c + 1) * 64 + prow0) * HDIM + pd0];
      pk1 = *(const uint4*)&wh_h[((long)(c + 1) * 64 + 32 + prow0) * HDIM + pd0];
    }
    f32x4 xacc[4] = {};
    if (c == js) {
      const ushort* whc = wh_h + (long)c * 64 * HDIM;
      f32x4 m[4] = {};
      #pragma unroll
      for (int s = 0; s < 2; ++s) {
        bf16x8 af = *(const bf16x8*)&whc[(long)(w * 16 + lane15) * HDIM + s * 32 + quad * 8];
        #pragma unroll
        for (int f = 0; f < 4; ++f)
          m[f] = MFMA16(af, frag(KT, f * 16 + lane15, s * 4 + quad), m[f]);
      }
      #pragma unroll
      for (int f = 0; f < 4; ++f)
        #pragma unroll
        for (int r = 0; r < 4; ++r) {
          int t = w * 16 + quad * 4 + r, j = f * 16 + lane15;
          XM[SWZE(j, t)] = (t > j) ? f2b(m[f][r]) : (ushort)0;
        }
      LGKBAR();
      const ushort* TBh = TB + ((long)h * 16 + c) * 4096;
      #pragma unroll
      for (int s = 0; s < 2; ++s) {
        bf16x8 af = *(const bf16x8*)&TBh[(long)(w * 16 + lane15) * 64 + s * 32 + quad * 8];
        #pragma unroll
        for (int f = 0; f < 4; ++f)
          xacc[f] = MFMA16(af, frag(XM, f * 16 + lane15, s * 4 + quad), xacc[f]);
      }
      LGKBAR();
    } else {
      // YB operand comes from registers prefetched last iteration
      #pragma unroll
      for (int f = 0; f < 4; ++f) {
        xacc[f] = MFMA16(ybr0, frag(KT, f * 16 + lane15, 0 * 4 + quad), xacc[f]);
        xacc[f] = MFMA16(ybr0, frag(nS, f * 16 + lane15, 0 * 4 + quad), xacc[f]);
        xacc[f] = MFMA16(ybr1, frag(KT, f * 16 + lane15, 1 * 4 + quad), xacc[f]);
        xacc[f] = MFMA16(ybr1, frag(nS, f * 16 + lane15, 1 * 4 + quad), xacc[f]);
      }
    }
    #pragma unroll
    for (int f = 0; f < 4; ++f)
      #pragma unroll
      for (int r = 0; r < 4; ++r)
        XM[SWZE(f * 16 + lane15, w * 16 + quad * 4 + r)] = f2b(xacc[f][r]);
    LGKBAR();
    {
      ushort* xt = X_h + (long)xidx * 4096;
      int j = tid >> 2, c2 = (tid & 3) * 2;
      bf16x8 s0 = frag(XM, j, c2);
      bf16x8 s1 = frag(XM, j, c2 + 1);
      *(bf16x8*)&xt[j * 64 + c2 * 8] = s0;
      *(bf16x8*)&xt[j * 64 + c2 * 8 + 8] = s1;
    }
    ++xidx;
    if (c < 15) {
      {
        const ushort* YBn = YB + ((long)h * 16 + c + 1) * 4096;
        ybr0 = *(const bf16x8*)&YBn[(long)(w * 16 + lane15) * 64 + 0 * 32 + quad * 8];
        ybr1 = *(const bf16x8*)&YBn[(long)(w * 16 + lane15) * 64 + 1 * 32 + quad * 8];
      }
      #pragma unroll
      for (int s = 0; s < 2; ++s) {
        bf16x8 aw = frag2(WT, w * 16 + lane15, s * 4 + quad);
        bf16x8 ax = frag(XM, w * 16 + lane15, s * 4 + quad);
        #pragma unroll
        for (int f = 0; f < 4; ++f) {
          Sacc[f] = MFMA16(aw, frag(XM, f * 16 + lane15, s * 4 + quad), Sacc[f]);
          Wacc[f] = MFMA16(ax, frag2(WT, f * 16 + lane15, s * 4 + quad), Wacc[f]);
        }
      }
      ushort* pz = KZ_h + (long)c * TTD * HDIM;
      #pragma unroll
      for (int f = 0; f < 4; ++f)
        #pragma unroll
        for (int r = 0; r < 4; ++r)
          pz[(long)(j0 + w * 16 + quad * 4 + r) * 64 + f * 16 + lane15] =
              f2b(kreg[f][r] - Wacc[f][r]);
      #pragma unroll
      for (int f = 0; f < 4; ++f)
        #pragma unroll
        for (int r = 0; r < 4; ++r)
          nS[SWZE(f * 16 + lane15, w * 16 + quad * 4 + r)] = f2b(-Sacc[f][r]);
    }
  }
}

// ---------------- flash: counted-vmcnt dbuf (stage-before-wait), exp2 + exact defer-max -----
__global__ __launch_bounds__(256) void flash_kernel(
    const ushort* __restrict__ qb, const ushort* __restrict__ kbuf,
    const ushort* __restrict__ whb, const ushort* __restrict__ Xb,
    const ushort* __restrict__ KZ, const ushort* __restrict__ vTb,
    ushort* __restrict__ oall)
{
  int h = blockIdx.x;
  int y = blockIdx.y;
  int ri = (y < 8) ? y : (23 - y);
  int r0 = ri * 64;
  const ushort* q_h = qb + (long)(h >> 1) * 64;
  const ushort* k_h = kbuf + (long)(h >> 1) * 64;
  const ushort* wh_h = whb + (long)h * TTD * HDIM;
  const ushort* X_h = Xb + (long)h * XT_PERH;
  const ushort* kz = KZ + ((long)h * 15 + (ri - 1)) * TTD * HDIM;
  const ushort* v_h = vTb + (long)(h >> 1) * 64 * TTD;

  __shared__ ushort S[2][3][4096];
  __shared__ ushort KD[4096];
  __shared__ ushort QWD[4096];
  __shared__ ushort PT[4096];

  int tid = threadIdx.x, w = tid >> 6, l = tid & 63;
  int quad = l >> 4, lane15 = l & 15;

  bf16x8 aq[2];
  #pragma unroll
  for (int s = 0; s < 2; ++s)
    aq[s] = *(const bf16x8*)&q_h[(long)(r0 + w * 16 + lane15) * DDM + s * 32 + quad * 8];
  // KD + jb=0 tiles staged early; QWD (wave-private) computed while loads fly
  const ushort* xst = X_h + (long)ri * 4096;   // packed tile (0, ri)
  stage_tile(k_h + (long)r0 * DDM, DDM, KD, w, l);
  if (ri > 0) stage_tile(kz, 64, &S[0][0][0], w, l);
  stage_tile(xst, 64, &S[0][1][0], w, l);
  stage_tile(v_h, TTD, &S[0][2][0], w, l);
  {
    f32x4 t4[4] = {};
    #pragma unroll
    for (int s = 0; s < 2; ++s)
      #pragma unroll
      for (int f = 0; f < 4; ++f) {
        bf16x8 bf = *(const bf16x8*)&wh_h[(long)(r0 + f * 16 + lane15) * HDIM + s * 32 + quad * 8];
        t4[f] = MFMA16(aq[s], bf, t4[f]);
      }
    #pragma unroll
    for (int f = 0; f < 4; ++f)
      #pragma unroll
      for (int r = 0; r < 4; ++r) {
        int i = w * 16 + quad * 4 + r, t = f * 16 + lane15;
        QWD[SWZE(i, t)] = (i >= t) ? f2b(-t4[f][r]) : (ushort)0;
      }
  }

  f32x4 O[4] = {};
  float m[4], lsum[4];
  #pragma unroll
  for (int r = 0; r < 4; ++r) { m[r] = -1e30f; lsum[r] = 0.f; }

  for (int jb = 0; jb <= ri; ++jb) {
    int cur = jb & 1;
    const ushort* xnx = xst + (long)(15 - jb) * 4096;  // packed tile (jb+1, ri)
    if (jb < ri) {
      long c0n = (long)(jb + 1) * 64;
      ushort* nb = &S[cur ^ 1][0][0];
      if (jb + 1 < ri) {
        stage_tile(kz + c0n * 64, 64, nb, w, l);
        stage_tile(xnx, 64, nb + 4096, w, l);
        stage_tile(v_h + c0n, TTD, nb + 8192, w, l);
        WAITVM(6);
      } else {
        stage_tile(xnx, 64, nb + 4096, w, l);
        stage_tile(v_h + c0n, TTD, nb + 8192, w, l);
        WAITVM(4);
      }
    } else {
      WAITVM(0);
    }
    BAR();
    const ushort* Skz = &S[cur][0][0];
    const ushort* Sx  = &S[cur][1][0];
    const ushort* Sv  = &S[cur][2][0];
    f32x4 acc[4] = {};
    const ushort* Sb = (jb < ri) ? Skz : KD;
    #pragma unroll
    for (int s = 0; s < 2; ++s)
      #pragma unroll
      for (int f = 0; f < 4; ++f)
        acc[f] = MFMA16(aq[s], frag(Sb, f * 16 + lane15, s * 4 + quad), acc[f]);
    #pragma unroll
    for (int s = 0; s < 2; ++s) {
      bf16x8 aw = frag(QWD, w * 16 + lane15, s * 4 + quad);
      #pragma unroll
      for (int f = 0; f < 4; ++f)
        acc[f] = MFMA16(aw, frag(Sx, f * 16 + lane15, s * 4 + quad), acc[f]);
    }
    float rmax[4] = {-3e38f, -3e38f, -3e38f, -3e38f};
    #pragma unroll
    for (int f = 0; f < 4; ++f)
      #pragma unroll
      for (int r = 0; r < 4; ++r) {
        float lv = acc[f][r] * PSC2;       // exp2 domain
        if (jb == ri && (f * 16 + lane15) > (w * 16 + quad * 4 + r)) lv = -3e38f;
        acc[f][r] = lv;
        rmax[r] = fmaxf(rmax[r], lv);
      }
    #pragma unroll
    for (int r = 0; r < 4; ++r) {
      rmax[r] = fmaxf(rmax[r], __shfl_xor(rmax[r], 1, 64));
      rmax[r] = fmaxf(rmax[r], __shfl_xor(rmax[r], 2, 64));
      rmax[r] = fmaxf(rmax[r], __shfl_xor(rmax[r], 4, 64));
      rmax[r] = fmaxf(rmax[r], __shfl_xor(rmax[r], 8, 64));
    }
    // exact defer-max: when no row's max grew (wave-wide), the rescale is identity
    bool grow = (rmax[0] > m[0]) | (rmax[1] > m[1]) | (rmax[2] > m[2]) | (rmax[3] > m[3]);
    if (__any(grow)) {
      float alpha[4];
      #pragma unroll
      for (int r = 0; r < 4; ++r) {
        float nm = fmaxf(m[r], rmax[r]);
        alpha[r] = exp2f(m[r] - nm);
        m[r] = nm;
        lsum[r] *= alpha[r];
      }
      #pragma unroll
      for (int f = 0; f < 4; ++f)
        #pragma unroll
        for (int r = 0; r < 4; ++r) O[f][r] *= alpha[r];
    }
    float rs[4] = {0.f, 0.f, 0.f, 0.f};
    #pragma unroll
    for (int f = 0; f < 4; ++f)
      #pragma unroll
      for (int r = 0; r < 4; ++r) {
        float e = exp2f(acc[f][r] - m[r]);
        acc[f][r] = e;
        rs[r] += e;
      }
    #pragma unroll
    for (int r = 0; r < 4; ++r) {
      rs[r] += __shfl_xor(rs[r], 1, 64);
      rs[r] += __shfl_xor(rs[r], 2, 64);
      rs[r] += __shfl_xor(rs[r], 4, 64);
      rs[r] += __shfl_xor(rs[r], 8, 64);
      lsum[r] += rs[r];
    }
    #pragma unroll
    for (int f = 0; f < 4; ++f)
      #pragma unroll
      for (int r = 0; r < 4; ++r) {
        int i = w * 16 + quad * 4 + r;
        PT[SWZE(i, f * 16 + lane15)] = f2b(acc[f][r]);
      }
    // PT is wave-private: lgkmcnt orders ds_write -> ds_read within the wave
    #pragma unroll
    for (int s = 0; s < 2; ++s) {
      bf16x8 ap = frag(PT, w * 16 + lane15, s * 4 + quad);
      #pragma unroll
      for (int f = 0; f < 4; ++f)
        O[f] = MFMA16(ap, frag(Sv, f * 16 + lane15, s * 4 + quad), O[f]);
    }
    BAR();   // readers done -> next iter may overwrite the other buffer
    xst = xnx;
  }
  #pragma unroll
  for (int r = 0; r < 4; ++r) lsum[r] = 1.f / lsum[r];
  #pragma unroll
  for (int f = 0; f < 4; ++f)
    #pragma unroll
    for (int r = 0; r < 4; ++r)
      oall[(long)(r0 + w * 16 + quad * 4 + r) * 2048 + h * 64 + f * 16 + lane15] =
          f2b(O[f][r] * lsum[r]);
}

// ---------------- final GEMM: out = o_all(bf16) @ ow_b^T (counted-vmcnt dbuf, BK=128) --------
__global__ __launch_bounds__(256) void gemm_out_kernel(
    const ushort* __restrict__ A, const ushort* __restrict__ Bb, float* __restrict__ C)
{
  __shared__ ushort Ab[2][8192];
  __shared__ ushort Bt[2][8192];
  int tid = threadIdx.x, w = tid >> 6, l = tid & 63;
  int quad = l >> 4, lane15 = l & 15;
  int rm = blockIdx.y * 64, cn = blockIdx.x * 64;
  const ushort* Ag = A + (long)rm * 2048;
  const ushort* Bg = Bb + (long)cn * 2048;

  stage_tile(Ag, 2048, &Ab[0][0], w, l);
  stage_tile(Ag + 64, 2048, &Ab[0][4096], w, l);
  stage_tile(Bg, 2048, &Bt[0][0], w, l);
  stage_tile(Bg + 64, 2048, &Bt[0][4096], w, l);

  f32x4 acc[4] = {};
  for (int kt = 0; kt < 16; ++kt) {
    int cur = kt & 1;
    if (kt < 15) {
      int nxt = cur ^ 1;
      long o = (long)(kt + 1) * 128;
      stage_tile(Ag + o, 2048, &Ab[nxt][0], w, l);
      stage_tile(Ag + o + 64, 2048, &Ab[nxt][4096], w, l);
      stage_tile(Bg + o, 2048, &Bt[nxt][0], w, l);
      stage_tile(Bg + o + 64, 2048, &Bt[nxt][4096], w, l);
      WAITVM(8);
    } else {
      WAITVM(0);
    }
    BAR();
    #pragma unroll
    for (int u = 0; u < 2; ++u)
      #pragma unroll
      for (int s = 0; s < 2; ++s) {
        bf16x8 af = frag(&Ab[cur][u * 4096], w * 16 + lane15, s * 4 + quad);
        #pragma unroll
        for (int f = 0; f < 4; ++f)
          acc[f] = MFMA16(af, frag(&Bt[cur][u * 4096], f * 16 + lane15, s * 4 + quad), acc[f]);
      }
    BAR();
  }
  int orow = rm + w * 16 + quad * 4;
  #pragma unroll
  for (int f = 0; f < 4; ++f)
    #pragma unroll
    for (int r = 0; r < 4; ++r)
      C[(long)(orow + r) * DDM + cn + f * 16 + lane15] = acc[f][r];
}

// ---------------- host ----------------
extern "C" void kernel_launch(void* const* d_in, const int* in_sizes, int n_in,
                              void* d_out, int out_size, void* d_ws, size_t ws_size,
                              hipStream_t stream) {
  const float* hs     = (const float*)d_in[0];
  const float* q_w    = (const float*)d_in[1];
  const float* k_w    = (const float*)d_in[2];
  const float* v_w    = (const float*)d_in[3];
  const float* w1     = (const float*)d_in[4];
  const float* w2     = (const float*)d_in[5];
  const float* conv_w = (const float*)d_in[6];
  const float* bt_w   = (const float*)d_in[7];
  const float* bt_b   = (const float*)d_in[8];
  const float* o_w    = (const float*)d_in[9];
  const float* omega  = (const float*)d_in[10];
  const float* phi    = (const float*)d_in[11];
  float* out = (float*)d_out;
  char* ws = (char*)d_ws;

  ushort* Xb     = (ushort*)(ws + OFF_X);
  ushort* KZb    = (ushort*)(ws + OFF_PZ);
  ushort* hs_b   = (ushort*)(ws + OFF_HSB);
  ushort* qw_wb  = (ushort*)(ws + OFF_QWW);
  ushort* kw_wb  = (ushort*)(ws + OFF_KWW);
  ushort* vw_wb  = (ushort*)(ws + OFF_VWW);
  ushort* w2_b   = (ushort*)(ws + OFF_W2B);
  ushort* wlow_b = (ushort*)(ws + OFF_WLOWB);
  ushort* TB     = (ushort*)(ws + OFF_TB);
  ushort* o_all  = (ushort*)(ws + OFF_OALL);
  ushort* YB     = (ushort*)(ws + OFF_YB);
  ushort* ow_b   = (ushort*)(ws + OFF_OWB);
  ushort* wh_b   = (ushort*)(ws + OFF_WHB);
  ushort* q_b    = (ushort*)(ws + OFF_QB);
  ushort* k_b    = (ushort*)(ws + OFF_KB);
  ushort* vT_b   = (ushort*)(ws + OFF_VTB);
  float*  beta   = (float*)(ws + OFF_BETA);
  ushort* bw_b   = (ushort*)(ws + OFF_BW64);

  CvtSegs sg;
  sg.src[0] = hs;   sg.dst[0] = hs_b;          sg.cnt[0] = 1048576;
  sg.src[1] = q_w;  sg.dst[1] = qw_wb;         sg.cnt[1] = 1048576;
  sg.src[2] = k_w;  sg.dst[2] = kw_wb;         sg.cnt[2] = 1048576;
  sg.src[3] = v_w;  sg.dst[3] = vw_wb;         sg.cnt[3] = 1048576;
  sg.src[4] = w2;   sg.dst[4] = w2_b;          sg.cnt[4] = 131072;
  sg.src[5] = bt_w; sg.dst[5] = bw_b;          sg.cnt[5] = 32768;
  sg.src[6] = w1;   sg.dst[6] = bw_b + 32768;  sg.cnt[6] = 32768;
  sg.src[7] = o_w;  sg.dst[7] = ow_b;          sg.cnt[7] = 2097152;
  cvt_all_kernel<<<dim3((CVT_TOTAL + 1023) / 1024), 256, 0, stream>>>(sg);

  qkv_sp_kernel<<<dim3(16, 8, 4), 256, 0, stream>>>(
      hs_b, qw_wb, kw_wb, vw_wb, bw_b, bt_b, q_b, k_b, vT_b, beta, wlow_b);

  wraw_solveA_kernel<<<dim3(16, 32), 256, 0, stream>>>(
      wlow_b, w2_b, conv_w, omega, phi, beta, wh_b, TB, YB);

  solveB_kernel<<<dim3(32, 16), 256, 0, stream>>>(wh_b, k_b, TB, YB, Xb, KZb);

  flash_kernel<<<dim3(32, 16), 256, 0, stream>>>(q_b, k_b, wh_b, Xb, KZb, vT_b, o_all);

  gemm_out_kernel<<<dim3(16, 16), 256, 0, stream>>>(o_all, ow_b, out);

  (void)in_sizes; (void)n_in; (void)out_size; (void)ws_size;
}

// Round 8
// 207.543 us; speedup vs baseline: 1.0592x; 1.0101x over previous
//
#include <hip/hip_runtime.h>
#include <math.h>

// ---------------- problem constants ----------------
#define TTD 1024
#define DDM 1024
#define HDIM 64
// PSCALE * log2(e): flash softmax runs in exp2 domain
#define PSC2 0.18033688011112042f
#define LS 72   // padded LDS stride (wraw_solveA)

typedef __attribute__((ext_vector_type(8))) __bf16 bf16x8;
typedef __attribute__((ext_vector_type(4))) float f32x4;
#define MFMA16(a,b,c) __builtin_amdgcn_mfma_f32_16x16x32_bf16(a,b,c,0,0,0)

// counted vmcnt wait + raw barriers (prefetch is ALWAYS issued before the wait point)
#define STR_(x) #x
#define WAITVM(N) asm volatile("s_waitcnt vmcnt(" STR_(N) ")" ::: "memory")
#define BAR() do { __builtin_amdgcn_s_barrier(); asm volatile("" ::: "memory"); } while (0)
#define LGKBAR() do { asm volatile("s_waitcnt lgkmcnt(0)" ::: "memory"); \
                      __builtin_amdgcn_s_barrier(); asm volatile("" ::: "memory"); } while (0)
#define FULLBAR() do { asm volatile("s_waitcnt vmcnt(0) lgkmcnt(0)" ::: "memory"); \
                       __builtin_amdgcn_s_barrier(); asm volatile("" ::: "memory"); } while (0)

__device__ __forceinline__ ushort f2b(float f) {
  unsigned u = __builtin_bit_cast(unsigned, f);
  return (ushort)((u + 0x7fffu + ((u >> 16) & 1u)) >> 16);
}
__device__ __forceinline__ float b2f(ushort u) {
  unsigned v = (unsigned)u << 16;
  return __builtin_bit_cast(float, v);
}

__device__ __forceinline__ void gload_lds16(const ushort* g, ushort* l) {
  __builtin_amdgcn_global_load_lds(
      (const __attribute__((address_space(1))) unsigned*)g,
      (__attribute__((address_space(3))) unsigned*)l, 16, 0, 0);
}

// XOR-swizzled 64x64 bf16 tile: 16B slot index for (row, chunk)
#define SWZ(row, cc) (((row) * 8 + ((cc) ^ ((row) & 7))) * 8)
#define SWZE(row, col) (SWZ(row, (col) >> 3) + ((col) & 7))
// transpose-write-friendly swizzle (solveB WT only): key = (row&7)^(row>>3).
#define SWZ2(row, cc) (((row) * 8 + ((cc) ^ (((row) & 7) ^ ((row) >> 3)))) * 8)
#define SWZ2E(row, col) (SWZ2(row, (col) >> 3) + ((col) & 7))

// async-stage one 64x64 tile (rows at gs-elem stride) into swizzled LDS tile
// issues exactly 2 global_load_lds instructions per thread
__device__ __forceinline__ void stage_tile(const ushort* gb, long gs, ushort* tile,
                                           int w, int l) {
  int sub = l >> 3, cc = (l & 7) ^ sub;
  #pragma unroll
  for (int it = 0; it < 2; ++it) {
    int q = w * 2 + it;
    gload_lds16(gb + (long)(q * 8 + sub) * gs + cc * 8, &tile[(q * 64 + l) * 8]);
  }
}

__device__ __forceinline__ bf16x8 frag(const ushort* tile, int row, int cc) {
  return *(const bf16x8*)&tile[SWZ(row, cc)];
}
__device__ __forceinline__ bf16x8 frag2(const ushort* tile, int row, int cc) {
  return *(const bf16x8*)&tile[SWZ2(row, cc)];
}

// ---------------- workspace layout (bytes); total used = 121,896,960 ----------
#define XT_PERH   557056L       // packed-UT X elems per head (136*4096)
#define OFF_X     0L            // 35,651,584 B
#define OFF_PZ    35651584L     // KZ bf16 [32][15][1024 j][64 d] : 60 MiB
// aliases inside KZ region (all dead before solveB writes KZ):
#define OFF_HSB   35651584L
#define OFF_QWW   37748736L
#define OFF_KWW   39845888L
#define OFF_VWW   41943040L
#define OFF_W2B   44040192L
#define OFF_WLOWB 44302336L
#define OFF_TB    98566144L     // Tbeta bf16 (wraw_solveA->solveB); dead after solveB
#define OFF_OALL  98566144L     // o_all overlays TB (flash writes after solveB)
#define OFF_YB    102760448L    // Yb bf16 (wraw_solveA->solveB)
#define OFF_OWB   106954752L    // ow_b own region: converted at t=0 by cvt_all
#define OFF_WHB   111149056L    // wh bf16 (live through flash)
#define OFF_QB    115343360L
#define OFF_KB    117440512L
#define OFF_VTB   119537664L
#define OFF_BETA  121634816L
#define OFF_BW64  121765888L    // 64x1024 bf16 [bt_w ; w1]

// ---------------- merged fp32 -> bf16 convert (8 segments, one launch) ----------------
#define CVT_TOTAL 6488064L
struct CvtSegs {
  const float* src[8];
  ushort* dst[8];
  long cnt[8];
};
__global__ __launch_bounds__(256) void cvt_all_kernel(CvtSegs sg) {
  long e = ((long)blockIdx.x * 256 + threadIdx.x) * 4;
  #pragma unroll
  for (int s = 0; s < 8; ++s) {
    if (e < sg.cnt[s]) {
      float4 f = *(const float4*)(sg.src[s] + e);
      ushort4 o;
      o.x = f2b(f.x); o.y = f2b(f.y); o.z = f2b(f.z); o.w = f2b(f.w);
      *(ushort4*)(sg.dst[s] + e) = o;
      return;
    }
    e -= sg.cnt[s];
  }
}

// ---------------- fused QKV + small projections: z in {Q,K,V, small} ----------------
// BM=128 x BN=64; counted-vmcnt dbuf: {stage next; WAITVM(6); BAR; compute; BAR}
// (prefetch issued BEFORE the wait point -> loads in flight across barrier+compute)
__global__ __launch_bounds__(256) void qkv_sp_kernel(
    const ushort* __restrict__ hsb,
    const ushort* __restrict__ wq, const ushort* __restrict__ wk, const ushort* __restrict__ wv,
    const ushort* __restrict__ bw, const float* __restrict__ bt_b,
    ushort* __restrict__ cq, ushort* __restrict__ ck, ushort* __restrict__ cv,
    float* __restrict__ beta, ushort* __restrict__ wlowb)
{
  int z = blockIdx.z;
  if (z == 3 && blockIdx.x != 0) return;
  const ushort* B = (z == 0) ? wq : (z == 1) ? wk : (z == 2) ? wv : bw;

  __shared__ ushort Ab[2][8192];   // two stacked swizzled 64x64 tiles (128 rows)
  __shared__ ushort Bb[2][4096];

  int tid = threadIdx.x, w = tid >> 6, l = tid & 63;
  int quad = l >> 4, lane15 = l & 15;
  int rm = blockIdx.y * 128, cn = (z == 3) ? 0 : blockIdx.x * 64;
  const ushort* Ag = hsb + (long)rm * DDM;
  const ushort* Bg = B + (long)cn * DDM;

  // prologue: stage tile 0 (6 vm insts)
  stage_tile(Ag, DDM, &Ab[0][0], w, l);
  stage_tile(Ag + 64 * DDM, DDM, &Ab[0][4096], w, l);
  stage_tile(Bg, DDM, &Bb[0][0], w, l);

  f32x4 acc[2][4] = {};
  int arow0 = (w & 1) * 32 + lane15;
  int asel = (w >> 1) * 4096;
  for (int kt = 0; kt < 16; ++kt) {
    int cur = kt & 1;
    if (kt < 15) {
      int nxt = cur ^ 1;
      stage_tile(Ag + (kt + 1) * 64, DDM, &Ab[nxt][0], w, l);
      stage_tile(Ag + 64 * DDM + (kt + 1) * 64, DDM, &Ab[nxt][4096], w, l);
      stage_tile(Bg + (kt + 1) * 64, DDM, &Bb[nxt][0], w, l);
      WAITVM(6);       // tile kt retired; tile kt+1's 6 loads stay in flight
    } else {
      WAITVM(0);
    }
    BAR();
    const ushort* Atile = &Ab[cur][asel];
    #pragma unroll
    for (int s = 0; s < 2; ++s) {
      bf16x8 a0 = frag(Atile, arow0, s * 4 + quad);
      bf16x8 a1 = frag(Atile, arow0 + 16, s * 4 + quad);
      #pragma unroll
      for (int f = 0; f < 4; ++f) {
        bf16x8 bf = frag(&Bb[cur][0], f * 16 + lane15, s * 4 + quad);
        acc[0][f] = MFMA16(a0, bf, acc[0][f]);
        acc[1][f] = MFMA16(a1, bf, acc[1][f]);
      }
    }
    BAR();             // readers done -> next iter may overwrite the other buffer
  }

  if (z < 2) {
    ushort* Cb = (z == 0) ? cq : ck;
    #pragma unroll
    for (int rr = 0; rr < 2; ++rr) {
      int orow = rm + w * 32 + rr * 16 + quad * 4;
      #pragma unroll
      for (int f = 0; f < 4; ++f)
        #pragma unroll
        for (int r = 0; r < 4; ++r)
          Cb[(long)(orow + r) * DDM + cn + f * 16 + lane15] = f2b(acc[rr][f][r]);
    }
  } else if (z == 2) {
    #pragma unroll
    for (int rr = 0; rr < 2; ++rr) {
      int orow = rm + w * 32 + rr * 16 + quad * 4;
      #pragma unroll
      for (int f = 0; f < 4; ++f) {
        ushort4 o;
        o.x = f2b(acc[rr][f][0]); o.y = f2b(acc[rr][f][1]);
        o.z = f2b(acc[rr][f][2]); o.w = f2b(acc[rr][f][3]);
        *(ushort4*)&cv[(long)(cn + f * 16 + lane15) * TTD + orow] = o;
      }
    }
  } else {
    #pragma unroll
    for (int rr = 0; rr < 2; ++rr) {
      int orow = rm + w * 32 + rr * 16 + quad * 4;
      #pragma unroll
      for (int f = 0; f < 2; ++f) {
        int hr = f * 16 + lane15;
        float bb = bt_b[hr];
        #pragma unroll
        for (int r = 0; r < 4; ++r)
          beta[(long)hr * TTD + orow + r] = 2.f / (1.f + __expf(-(acc[rr][f][r] + bb)));
      }
      #pragma unroll
      for (int f = 2; f < 4; ++f)
        #pragma unroll
        for (int r = 0; r < 4; ++r)
          wlowb[(long)(orow + r) * 32 + (f - 2) * 16 + lane15] = f2b(acc[rr][f][r]);
    }
  }
}

// ---------------- FUSED: w_raw GEMM + conv + SiLU + rotate + normalize + solveA -------------
__global__ __launch_bounds__(256) void wraw_solveA_kernel(
    const ushort* __restrict__ wlowb, const ushort* __restrict__ w2b,
    const float* __restrict__ conv_w, const float* __restrict__ omega,
    const float* __restrict__ phi, const float* __restrict__ beta,
    ushort* __restrict__ whb, ushort* __restrict__ TB, ushort* __restrict__ YB)
{
  int c = blockIdx.x;
  int rm = c * 64;
  int p = blockIdx.y;             // head hr
  int hkv = p >> 1, r = p & 1;
  int c0 = hkv * 256 + r * 128;

  __shared__ char pool_[65568];
  ushort* As = (ushort*)pool_;
  ushort* Bs = (ushort*)(pool_ + 4096);
  float (*WR)[132] = (float(*)[132])(pool_ + 12288);
  ushort* Wrow = (ushort*)(pool_ + 47136);   // wh row-major [t][d], stride LS
  ushort* WT   = (ushort*)(pool_ + 56352);   // wh transposed [d][t], stride LS
  float (*Lm)[65] = (float(*)[65])pool_;
  float (*Vf)[65] = (float(*)[65])(pool_ + 16640);
  ushort* Tb = (ushort*)(pool_ + 33280);

  int tid = threadIdx.x, w = tid >> 6, l = tid & 63;
  int quad = l >> 4, lane15 = l & 15;

  // ---- phase 1: async-stage A (w_low rows) + B (w2 rows, 128) ----
  {
    int row = tid >> 2, ch = (tid & 3) * 8;
    gload_lds16(wlowb + (long)(rm + row) * 32 + ch, &As[row * 32 + ch]);
    gload_lds16(w2b + (long)(c0 + row) * 32 + ch, &Bs[row * 32 + ch]);
    gload_lds16(w2b + (long)(c0 + 64 + row) * 32 + ch, &Bs[(64 + row) * 32 + ch]);
  }
  // halo rows rm-2, rm-1 (VALU dot; zero when rm==0 -> causal pad)
  {
    int hr2 = tid >> 7, col = tid & 127;
    float acc = 0.f;
    if (rm > 0) {
      long t = rm - 2 + hr2;
      for (int k = 0; k < 32; ++k)
        acc += b2f(wlowb[t * 32 + k]) * b2f(w2b[(long)(c0 + col) * 32 + k]);
    }
    WR[hr2][col] = acc;
  }
  FULLBAR();   // async stage consumed next

  // ---- phase 2: main 64x128 GEMM via MFMA (two 64-col halves) ----
  #pragma unroll
  for (int g = 0; g < 2; ++g) {
    f32x4 acc[4] = {};
    bf16x8 af = *(const bf16x8*)&As[(w * 16 + lane15) * 32 + quad * 8];
    #pragma unroll
    for (int f = 0; f < 4; ++f) {
      bf16x8 bf = *(const bf16x8*)&Bs[(g * 64 + f * 16 + lane15) * 32 + quad * 8];
      acc[f] = MFMA16(af, bf, acc[f]);
    }
    #pragma unroll
    for (int f = 0; f < 4; ++f)
      #pragma unroll
      for (int rr = 0; rr < 4; ++rr)
        WR[2 + w * 16 + quad * 4 + rr][g * 64 + f * 16 + lane15] = acc[f][rr];
  }
  LGKBAR();

  // ---- phase 3: conv(K=3) + SiLU + rotate + L2 normalize (fast transcendentals;
  //      outputs are bf16-rounded so ~21-bit intrinsics are within tolerance) ----
  {
    float cwa[3], cwb[3];
    #pragma unroll
    for (int i = 0; i < 3; ++i) {
      cwa[i] = conv_w[(long)(c0 + l) * 3 + i];
      cwb[i] = conv_w[(long)(c0 + 64 + l) * 3 + i];
    }
    float om = omega[r], ph = phi[r];
    for (int it = 0; it < 16; ++it) {
      int tl = it * 4 + w;
      int t = rm + tl;
      float a = cwa[0] * WR[tl][l] + cwa[1] * WR[tl + 1][l] + cwa[2] * WR[tl + 2][l];
      float b = cwb[0] * WR[tl][64 + l] + cwb[1] * WR[tl + 1][64 + l] + cwb[2] * WR[tl + 2][64 + l];
      a = a / (1.f + __expf(-a));
      b = b / (1.f + __expf(-b));
      float th = om * (float)t + ph;
      float wd = a * __cosf(th) + b * __sinf(th);
      float ss = wd * wd;
      #pragma unroll
      for (int o = 32; o > 0; o >>= 1) ss += __shfl_xor(ss, o, 64);
      ushort hv = f2b(wd * (1.f / sqrtf(ss + 1e-6f)));
      whb[((long)p * TTD + t) * HDIM + l] = hv;
      Wrow[tl * LS + l] = hv;
      WT[l * LS + tl] = hv;
    }
  }
  LGKBAR();   // WR reads done (Lm/Vf/Tb may overlay); Wrow/WT complete

  // ---- phase 4: solveA on this chunk ----
  const float* bet = beta + (long)p * TTD + rm;
  ushort* TBh = TB + ((long)p * 16 + c) * 4096;
  ushort* YBh = YB + ((long)p * 16 + c) * 4096;

  f32x4 g4[4] = {};
  #pragma unroll
  for (int s = 0; s < 2; ++s) {
    bf16x8 af = *(const bf16x8*)&Wrow[(w * 16 + lane15) * LS + s * 32 + quad * 8];
    #pragma unroll
    for (int f = 0; f < 4; ++f) {
      bf16x8 bf = *(const bf16x8*)&Wrow[(f * 16 + lane15) * LS + s * 32 + quad * 8];
      g4[f] = MFMA16(af, bf, g4[f]);
    }
  }
  #pragma unroll
  for (int r4 = 0; r4 < 4; ++r4) {
    int t = w * 16 + quad * 4 + r4;
    float bv = bet[t];
    #pragma unroll
    for (int f = 0; f < 4; ++f) {
      int tp = f * 16 + lane15;
      Lm[t][tp] = (t > tp) ? bv * g4[f][r4] : 0.f;
    }
  }
  LGKBAR();

  {
    float cur[16];
    #pragma unroll
    for (int i = 0; i < 16; ++i) cur[i] = (w * 16 + i == l) ? bet[l] : 0.f;
    for (int sb = 0; sb < 4; ++sb) {
      if (w == sb) {
        float xloc[16];
        #pragma unroll
        for (int i = 0; i < 16; ++i) {
          float bv = cur[i];
          #pragma unroll
          for (int j2 = 0; j2 < 16; ++j2)
            if (j2 < i) bv -= Lm[sb * 16 + i][sb * 16 + j2] * xloc[j2];
          xloc[i] = bv;
          Vf[sb * 16 + i][l] = bv;
        }
      }
      LGKBAR();
      if (w > sb) {
        float xp[16];
        #pragma unroll
        for (int t = 0; t < 16; ++t) xp[t] = Vf[sb * 16 + t][l];
        #pragma unroll
        for (int i = 0; i < 16; ++i) {
          float s2 = cur[i];
          #pragma unroll
          for (int t = 0; t < 16; ++t) s2 -= Lm[w * 16 + i][sb * 16 + t] * xp[t];
          cur[i] = s2;
        }
      }
    }
  }
  {
    int t = tid >> 2, off = (tid & 3) * 16;
    ushort tmp[16];
    #pragma unroll
    for (int i = 0; i < 16; ++i) { tmp[i] = f2b(Vf[t][off + i]); Tb[t * LS + off + i] = tmp[i]; }
    *(uint4*)&TBh[t * 64 + off] = *(const uint4*)&tmp[0];
    *(uint4*)&TBh[t * 64 + off + 8] = *(const uint4*)&tmp[8];
  }
  LGKBAR();
  f32x4 y[4] = {};
  #pragma unroll
  for (int s = 0; s < 2; ++s) {
    bf16x8 af = *(const bf16x8*)&Tb[(w * 16 + lane15) * LS + s * 32 + quad * 8];
    #pragma unroll
    for (int f = 0; f < 4; ++f) {
      bf16x8 bf = *(const bf16x8*)&WT[(f * 16 + lane15) * LS + s * 32 + quad * 8];
      y[f] = MFMA16(af, bf, y[f]);
    }
  }
  #pragma unroll
  for (int f = 0; f < 4; ++f)
    #pragma unroll
    for (int r4 = 0; r4 < 4; ++r4)
      YBh[(long)(w * 16 + quad * 4 + r4) * 64 + f * 16 + lane15] = f2b(y[f][r4]);
}

// ---------------- solveB: chunk recurrence; reg-prefetched whc/YB; SWZ2 WT ------------------
__global__ __launch_bounds__(256) void solveB_kernel(
    const ushort* __restrict__ whb, const ushort* __restrict__ kb,
    const ushort* __restrict__ TB, const ushort* __restrict__ YB,
    ushort* __restrict__ Xb, ushort* __restrict__ KZ)
{
  int h = blockIdx.x;
  int ty = blockIdx.y;
  int js = (ty < 8) ? ty : (23 - ty);
  int j0 = js * 64;
  const ushort* wh_h = whb + (long)h * TTD * HDIM;
  const ushort* k_h = kb + (long)(h >> 1) * 64;
  ushort* X_h = Xb + (long)h * XT_PERH;
  ushort* KZ_h = KZ + (long)h * 15 * TTD * HDIM;
  int xidx = js * 16 - js * (js - 1) / 2;   // packed tile index for (js, c=js)

  __shared__ ushort KT[4096];
  __shared__ ushort WT[4096];   // SWZ2-swizzled (transpose-write-friendly)
  __shared__ ushort XM[4096];
  __shared__ ushort nS[4096];

  int tid = threadIdx.x, w = tid >> 6, l = tid & 63;
  int quad = l >> 4, lane15 = l & 15;
  f32x4 Sacc[4] = {}, Wacc[4] = {};

  stage_tile(k_h + (long)j0 * DDM, DDM, KT, w, l);

  float kreg[4][4];
  #pragma unroll
  for (int f = 0; f < 4; ++f)
    #pragma unroll
    for (int r = 0; r < 4; ++r)
      kreg[f][r] = b2f(k_h[(long)(j0 + w * 16 + quad * 4 + r) * DDM + f * 16 + lane15]);

  // whc prefetch: thread covers rows {prow0, 32+prow0}, d-chunk pd0..pd0+7
  int prow0 = tid >> 3, pd0 = (tid & 7) * 8;
  uint4 pk0 = *(const uint4*)&wh_h[((long)js * 64 + prow0) * HDIM + pd0];
  uint4 pk1 = *(const uint4*)&wh_h[((long)js * 64 + 32 + prow0) * HDIM + pd0];
  bf16x8 ybr0 = {}, ybr1 = {};   // YB prefetch (valid from second iteration on)

  WAITVM(0);   // KT async stage landed

  for (int c = js; c < 16; ++c) {
    LGKBAR();
    // WT write from prefetched regs (conflict-free via SWZ2)
    {
      const ushort* pu0 = (const ushort*)&pk0;
      const ushort* pu1 = (const ushort*)&pk1;
      #pragma unroll
      for (int i = 0; i < 8; ++i) WT[SWZ2E(pd0 + i, prow0)] = pu0[i];
      #pragma unroll
      for (int i = 0; i < 8; ++i) WT[SWZ2E(pd0 + i, 32 + prow0)] = pu1[i];
    }
    // issue whc prefetch for c+1 (covered by this whole iteration)
    if (c < 15) {
      pk0 = *(const uint4*)&wh_h[((long)(c + 1) * 64 + prow0) * HDIM + pd0];
      pk1 = *(const uint4*)&wh_h[((long)(c + 1) * 64 + 32 + prow0) * HDIM + pd0];
    }
    f32x4 xacc[4] = {};
    if (c == js) {
      const ushort* whc = wh_h + (long)c * 64 * HDIM;
      f32x4 m[4] = {};
      #pragma unroll
      for (int s = 0; s < 2; ++s) {
        bf16x8 af = *(const bf16x8*)&whc[(long)(w * 16 + lane15) * HDIM + s * 32 + quad * 8];
        #pragma unroll
        for (int f = 0; f < 4; ++f)
          m[f] = MFMA16(af, frag(KT, f * 16 + lane15, s * 4 + quad), m[f]);
      }
      #pragma unroll
      for (int f = 0; f < 4; ++f)
        #pragma unroll
        for (int r = 0; r < 4; ++r) {
          int t = w * 16 + quad * 4 + r, j = f * 16 + lane15;
          XM[SWZE(j, t)] = (t > j) ? f2b(m[f][r]) : (ushort)0;
        }
      LGKBAR();
      const ushort* TBh = TB + ((long)h * 16 + c) * 4096;
      #pragma unroll
      for (int s = 0; s < 2; ++s) {
        bf16x8 af = *(const bf16x8*)&TBh[(long)(w * 16 + lane15) * 64 + s * 32 + quad * 8];
        #pragma unroll
        for (int f = 0; f < 4; ++f)
          xacc[f] = MFMA16(af, frag(XM, f * 16 + lane15, s * 4 + quad), xacc[f]);
      }
      LGKBAR();
    } else {
      // YB operand comes from registers prefetched last iteration
      #pragma unroll
      for (int f = 0; f < 4; ++f) {
        xacc[f] = MFMA16(ybr0, frag(KT, f * 16 + lane15, 0 * 4 + quad), xacc[f]);
        xacc[f] = MFMA16(ybr0, frag(nS, f * 16 + lane15, 0 * 4 + quad), xacc[f]);
        xacc[f] = MFMA16(ybr1, frag(KT, f * 16 + lane15, 1 * 4 + quad), xacc[f]);
        xacc[f] = MFMA16(ybr1, frag(nS, f * 16 + lane15, 1 * 4 + quad), xacc[f]);
      }
    }
    #pragma unroll
    for (int f = 0; f < 4; ++f)
      #pragma unroll
      for (int r = 0; r < 4; ++r)
        XM[SWZE(f * 16 + lane15, w * 16 + quad * 4 + r)] = f2b(xacc[f][r]);
    LGKBAR();
    {
      ushort* xt = X_h + (long)xidx * 4096;
      int j = tid >> 2, c2 = (tid & 3) * 2;
      bf16x8 s0 = frag(XM, j, c2);
      bf16x8 s1 = frag(XM, j, c2 + 1);
      *(bf16x8*)&xt[j * 64 + c2 * 8] = s0;
      *(bf16x8*)&xt[j * 64 + c2 * 8 + 8] = s1;
    }
    ++xidx;
    if (c < 15) {
      {
        const ushort* YBn = YB + ((long)h * 16 + c + 1) * 4096;
        ybr0 = *(const bf16x8*)&YBn[(long)(w * 16 + lane15) * 64 + 0 * 32 + quad * 8];
        ybr1 = *(const bf16x8*)&YBn[(long)(w * 16 + lane15) * 64 + 1 * 32 + quad * 8];
      }
      #pragma unroll
      for (int s = 0; s < 2; ++s) {
        bf16x8 aw = frag2(WT, w * 16 + lane15, s * 4 + quad);
        bf16x8 ax = frag(XM, w * 16 + lane15, s * 4 + quad);
        #pragma unroll
        for (int f = 0; f < 4; ++f) {
          Sacc[f] = MFMA16(aw, frag(XM, f * 16 + lane15, s * 4 + quad), Sacc[f]);
          Wacc[f] = MFMA16(ax, frag2(WT, f * 16 + lane15, s * 4 + quad), Wacc[f]);
        }
      }
      ushort* pz = KZ_h + (long)c * TTD * HDIM;
      #pragma unroll
      for (int f = 0; f < 4; ++f)
        #pragma unroll
        for (int r = 0; r < 4; ++r)
          pz[(long)(j0 + w * 16 + quad * 4 + r) * 64 + f * 16 + lane15] =
              f2b(kreg[f][r] - Wacc[f][r]);
      #pragma unroll
      for (int f = 0; f < 4; ++f)
        #pragma unroll
        for (int r = 0; r < 4; ++r)
          nS[SWZE(f * 16 + lane15, w * 16 + quad * 4 + r)] = f2b(-Sacc[f][r]);
    }
  }
}

// ---------------- flash: counted-vmcnt dbuf; exp2 + exact defer-max; MFMA row-sum ----------
// lsum is computed by the matrix pipe: a 5th PV accumulator O5 with an all-ones B operand
// gives O5[r] = sum_k P[row][k], accumulated across tiles under the same alpha rescale as O.
// Removes the 16-shfl rs reduce per iteration (shuffles are ds-pipe ops, serial chain).
__global__ __launch_bounds__(256) void flash_kernel(
    const ushort* __restrict__ qb, const ushort* __restrict__ kbuf,
    const ushort* __restrict__ whb, const ushort* __restrict__ Xb,
    const ushort* __restrict__ KZ, const ushort* __restrict__ vTb,
    ushort* __restrict__ oall)
{
  int h = blockIdx.x;
  int y = blockIdx.y;
  int ri = (y < 8) ? y : (23 - y);
  int r0 = ri * 64;
  const ushort* q_h = qb + (long)(h >> 1) * 64;
  const ushort* k_h = kbuf + (long)(h >> 1) * 64;
  const ushort* wh_h = whb + (long)h * TTD * HDIM;
  const ushort* X_h = Xb + (long)h * XT_PERH;
  const ushort* kz = KZ + ((long)h * 15 + (ri - 1)) * TTD * HDIM;
  const ushort* v_h = vTb + (long)(h >> 1) * 64 * TTD;

  __shared__ ushort S[2][3][4096];
  __shared__ ushort KD[4096];
  __shared__ ushort QWD[4096];
  __shared__ ushort PT[4096];

  int tid = threadIdx.x, w = tid >> 6, l = tid & 63;
  int quad = l >> 4, lane15 = l & 15;

  bf16x8 aq[2];
  #pragma unroll
  for (int s = 0; s < 2; ++s)
    aq[s] = *(const bf16x8*)&q_h[(long)(r0 + w * 16 + lane15) * DDM + s * 32 + quad * 8];
  // all-ones bf16 B operand for the row-sum MFMA
  bf16x8 kones;
  #pragma unroll
  for (int i = 0; i < 8; ++i) kones[i] = (__bf16)1.0f;
  // KD + jb=0 tiles staged early; QWD (wave-private) computed while loads fly
  const ushort* xst = X_h + (long)ri * 4096;   // packed tile (0, ri)
  stage_tile(k_h + (long)r0 * DDM, DDM, KD, w, l);
  if (ri > 0) stage_tile(kz, 64, &S[0][0][0], w, l);
  stage_tile(xst, 64, &S[0][1][0], w, l);
  stage_tile(v_h, TTD, &S[0][2][0], w, l);
  {
    f32x4 t4[4] = {};
    #pragma unroll
    for (int s = 0; s < 2; ++s)
      #pragma unroll
      for (int f = 0; f < 4; ++f) {
        bf16x8 bf = *(const bf16x8*)&wh_h[(long)(r0 + f * 16 + lane15) * HDIM + s * 32 + quad * 8];
        t4[f] = MFMA16(aq[s], bf, t4[f]);
      }
    #pragma unroll
    for (int f = 0; f < 4; ++f)
      #pragma unroll
      for (int r = 0; r < 4; ++r) {
        int i = w * 16 + quad * 4 + r, t = f * 16 + lane15;
        QWD[SWZE(i, t)] = (i >= t) ? f2b(-t4[f][r]) : (ushort)0;
      }
  }

  f32x4 O[4] = {};
  f32x4 O5 = {};                 // row-sum accumulator (== lsum)
  float m[4];
  #pragma unroll
  for (int r = 0; r < 4; ++r) m[r] = -1e30f;

  for (int jb = 0; jb <= ri; ++jb) {
    int cur = jb & 1;
    const ushort* xnx = xst + (long)(15 - jb) * 4096;  // packed tile (jb+1, ri)
    if (jb < ri) {
      long c0n = (long)(jb + 1) * 64;
      ushort* nb = &S[cur ^ 1][0][0];
      if (jb + 1 < ri) {
        stage_tile(kz + c0n * 64, 64, nb, w, l);
        stage_tile(xnx, 64, nb + 4096, w, l);
        stage_tile(v_h + c0n, TTD, nb + 8192, w, l);
        WAITVM(6);
      } else {
        stage_tile(xnx, 64, nb + 4096, w, l);
        stage_tile(v_h + c0n, TTD, nb + 8192, w, l);
        WAITVM(4);
      }
    } else {
      WAITVM(0);
    }
    BAR();
    const ushort* Skz = &S[cur][0][0];
    const ushort* Sx  = &S[cur][1][0];
    const ushort* Sv  = &S[cur][2][0];
    f32x4 acc[4] = {};
    const ushort* Sb = (jb < ri) ? Skz : KD;
    #pragma unroll
    for (int s = 0; s < 2; ++s)
      #pragma unroll
      for (int f = 0; f < 4; ++f)
        acc[f] = MFMA16(aq[s], frag(Sb, f * 16 + lane15, s * 4 + quad), acc[f]);
    #pragma unroll
    for (int s = 0; s < 2; ++s) {
      bf16x8 aw = frag(QWD, w * 16 + lane15, s * 4 + quad);
      #pragma unroll
      for (int f = 0; f < 4; ++f)
        acc[f] = MFMA16(aw, frag(Sx, f * 16 + lane15, s * 4 + quad), acc[f]);
    }
    float rmax[4] = {-3e38f, -3e38f, -3e38f, -3e38f};
    #pragma unroll
    for (int f = 0; f < 4; ++f)
      #pragma unroll
      for (int r = 0; r < 4; ++r) {
        float lv = acc[f][r] * PSC2;       // exp2 domain
        if (jb == ri && (f * 16 + lane15) > (w * 16 + quad * 4 + r)) lv = -3e38f;
        acc[f][r] = lv;
        rmax[r] = fmaxf(rmax[r], lv);
      }
    #pragma unroll
    for (int r = 0; r < 4; ++r) {
      rmax[r] = fmaxf(rmax[r], __shfl_xor(rmax[r], 1, 64));
      rmax[r] = fmaxf(rmax[r], __shfl_xor(rmax[r], 2, 64));
      rmax[r] = fmaxf(rmax[r], __shfl_xor(rmax[r], 4, 64));
      rmax[r] = fmaxf(rmax[r], __shfl_xor(rmax[r], 8, 64));
    }
    // exact defer-max: when no row's max grew (wave-wide), the rescale is identity
    bool grow = (rmax[0] > m[0]) | (rmax[1] > m[1]) | (rmax[2] > m[2]) | (rmax[3] > m[3]);
    if (__any(grow)) {
      float alpha[4];
      #pragma unroll
      for (int r = 0; r < 4; ++r) {
        float nm = fmaxf(m[r], rmax[r]);
        alpha[r] = exp2f(m[r] - nm);
        m[r] = nm;
        O5[r] *= alpha[r];
      }
      #pragma unroll
      for (int f = 0; f < 4; ++f)
        #pragma unroll
        for (int r = 0; r < 4; ++r) O[f][r] *= alpha[r];
    }
    #pragma unroll
    for (int f = 0; f < 4; ++f)
      #pragma unroll
      for (int r = 0; r < 4; ++r)
        acc[f][r] = exp2f(acc[f][r] - m[r]);
    #pragma unroll
    for (int f = 0; f < 4; ++f)
      #pragma unroll
      for (int r = 0; r < 4; ++r) {
        int i = w * 16 + quad * 4 + r;
        PT[SWZE(i, f * 16 + lane15)] = f2b(acc[f][r]);
      }
    // PT is wave-private: lgkmcnt orders ds_write -> ds_read within the wave
    #pragma unroll
    for (int s = 0; s < 2; ++s) {
      bf16x8 ap = frag(PT, w * 16 + lane15, s * 4 + quad);
      #pragma unroll
      for (int f = 0; f < 4; ++f)
        O[f] = MFMA16(ap, frag(Sv, f * 16 + lane15, s * 4 + quad), O[f]);
      O5 = MFMA16(ap, kones, O5);      // row-sum via matrix pipe
    }
    BAR();   // readers done -> next iter may overwrite the other buffer
    xst = xnx;
  }
  float lsum[4];
  #pragma unroll
  for (int r = 0; r < 4; ++r) lsum[r] = 1.f / O5[r];
  #pragma unroll
  for (int f = 0; f < 4; ++f)
    #pragma unroll
    for (int r = 0; r < 4; ++r)
      oall[(long)(r0 + w * 16 + quad * 4 + r) * 2048 + h * 64 + f * 16 + lane15] =
          f2b(O[f][r] * lsum[r]);
}

// ---------------- final GEMM: out = o_all(bf16) @ ow_b^T (counted-vmcnt dbuf, BK=128) --------
__global__ __launch_bounds__(256) void gemm_out_kernel(
    const ushort* __restrict__ A, const ushort* __restrict__ Bb, float* __restrict__ C)
{
  __shared__ ushort Ab[2][8192];
  __shared__ ushort Bt[2][8192];
  int tid = threadIdx.x, w = tid >> 6, l = tid & 63;
  int quad = l >> 4, lane15 = l & 15;
  int rm = blockIdx.y * 64, cn = blockIdx.x * 64;
  const ushort* Ag = A + (long)rm * 2048;
  const ushort* Bg = Bb + (long)cn * 2048;

  stage_tile(Ag, 2048, &Ab[0][0], w, l);
  stage_tile(Ag + 64, 2048, &Ab[0][4096], w, l);
  stage_tile(Bg, 2048, &Bt[0][0], w, l);
  stage_tile(Bg + 64, 2048, &Bt[0][4096], w, l);

  f32x4 acc[4] = {};
  for (int kt = 0; kt < 16; ++kt) {
    int cur = kt & 1;
    if (kt < 15) {
      int nxt = cur ^ 1;
      long o = (long)(kt + 1) * 128;
      stage_tile(Ag + o, 2048, &Ab[nxt][0], w, l);
      stage_tile(Ag + o + 64, 2048, &Ab[nxt][4096], w, l);
      stage_tile(Bg + o, 2048, &Bt[nxt][0], w, l);
      stage_tile(Bg + o + 64, 2048, &Bt[nxt][4096], w, l);
      WAITVM(8);
    } else {
      WAITVM(0);
    }
    BAR();
    #pragma unroll
    for (int u = 0; u < 2; ++u)
      #pragma unroll
      for (int s = 0; s < 2; ++s) {
        bf16x8 af = frag(&Ab[cur][u * 4096], w * 16 + lane15, s * 4 + quad);
        #pragma unroll
        for (int f = 0; f < 4; ++f)
          acc[f] = MFMA16(af, frag(&Bt[cur][u * 4096], f * 16 + lane15, s * 4 + quad), acc[f]);
      }
    BAR();
  }
  int orow = rm + w * 16 + quad * 4;
  #pragma unroll
  for (int f = 0; f < 4; ++f)
    #pragma unroll
    for (int r = 0; r < 4; ++r)
      C[(long)(orow + r) * DDM + cn + f * 16 + lane15] = acc[f][r];
}

// ---------------- host ----------------
extern "C" void kernel_launch(void* const* d_in, const int* in_sizes, int n_in,
                              void* d_out, int out_size, void* d_ws, size_t ws_size,
                              hipStream_t stream) {
  const float* hs     = (const float*)d_in[0];
  const float* q_w    = (const float*)d_in[1];
  const float* k_w    = (const float*)d_in[2];
  const float* v_w    = (const float*)d_in[3];
  const float* w1     = (const float*)d_in[4];
  const float* w2     = (const float*)d_in[5];
  const float* conv_w = (const float*)d_in[6];
  const float* bt_w   = (const float*)d_in[7];
  const float* bt_b   = (const float*)d_in[8];
  const float* o_w    = (const float*)d_in[9];
  const float* omega  = (const float*)d_in[10];
  const float* phi    = (const float*)d_in[11];
  float* out = (float*)d_out;
  char* ws = (char*)d_ws;

  ushort* Xb     = (ushort*)(ws + OFF_X);
  ushort* KZb    = (ushort*)(ws + OFF_PZ);
  ushort* hs_b   = (ushort*)(ws + OFF_HSB);
  ushort* qw_wb  = (ushort*)(ws + OFF_QWW);
  ushort* kw_wb  = (ushort*)(ws + OFF_KWW);
  ushort* vw_wb  = (ushort*)(ws + OFF_VWW);
  ushort* w2_b   = (ushort*)(ws + OFF_W2B);
  ushort* wlow_b = (ushort*)(ws + OFF_WLOWB);
  ushort* TB     = (ushort*)(ws + OFF_TB);
  ushort* o_all  = (ushort*)(ws + OFF_OALL);
  ushort* YB     = (ushort*)(ws + OFF_YB);
  ushort* ow_b   = (ushort*)(ws + OFF_OWB);
  ushort* wh_b   = (ushort*)(ws + OFF_WHB);
  ushort* q_b    = (ushort*)(ws + OFF_QB);
  ushort* k_b    = (ushort*)(ws + OFF_KB);
  ushort* vT_b   = (ushort*)(ws + OFF_VTB);
  float*  beta   = (float*)(ws + OFF_BETA);
  ushort* bw_b   = (ushort*)(ws + OFF_BW64);

  CvtSegs sg;
  sg.src[0] = hs;   sg.dst[0] = hs_b;          sg.cnt[0] = 1048576;
  sg.src[1] = q_w;  sg.dst[1] = qw_wb;         sg.cnt[1] = 1048576;
  sg.src[2] = k_w;  sg.dst[2] = kw_wb;         sg.cnt[2] = 1048576;
  sg.src[3] = v_w;  sg.dst[3] = vw_wb;         sg.cnt[3] = 1048576;
  sg.src[4] = w2;   sg.dst[4] = w2_b;          sg.cnt[4] = 131072;
  sg.src[5] = bt_w; sg.dst[5] = bw_b;          sg.cnt[5] = 32768;
  sg.src[6] = w1;   sg.dst[6] = bw_b + 32768;  sg.cnt[6] = 32768;
  sg.src[7] = o_w;  sg.dst[7] = ow_b;          sg.cnt[7] = 2097152;
  cvt_all_kernel<<<dim3((CVT_TOTAL + 1023) / 1024), 256, 0, stream>>>(sg);

  qkv_sp_kernel<<<dim3(16, 8, 4), 256, 0, stream>>>(
      hs_b, qw_wb, kw_wb, vw_wb, bw_b, bt_b, q_b, k_b, vT_b, beta, wlow_b);

  wraw_solveA_kernel<<<dim3(16, 32), 256, 0, stream>>>(
      wlow_b, w2_b, conv_w, omega, phi, beta, wh_b, TB, YB);

  solveB_kernel<<<dim3(32, 16), 256, 0, stream>>>(wh_b, k_b, TB, YB, Xb, KZb);

  flash_kernel<<<dim3(32, 16), 256, 0, stream>>>(q_b, k_b, wh_b, Xb, KZb, vT_b, o_all);

  gemm_out_kernel<<<dim3(16, 16), 256, 0, stream>>>(o_all, ow_b, out);

  (void)in_sizes; (void)n_in; (void)out_size; (void)ws_size;
}